// Round 2
// baseline (16649.393 us; speedup 1.0000x reference)
//
#include <hip/hip_runtime.h>
#include <hip/hip_bf16.h>
#include <math.h>

// Fixed problem dims
static constexpr int nB = 8, nT = 512, nE = 1024, nL = 8, nD = 512;
static constexpr int nBT = nB * nT;   // 4096 rows (b,t)
static constexpr int nLD = nL * nD;   // 4096

__device__ __forceinline__ float gelu_f(float x) {
    return 0.5f * x * (1.0f + erff(x * 0.70710678118654752f));  // exact GELU
}

// dst[r] = sum_i src[r,i] * (w ? w[i] : 1)
__global__ __launch_bounds__(256) void k_wdot(const float* __restrict__ src,
                                              const float* __restrict__ w,
                                              float* __restrict__ dst,
                                              int rows, int rowlen) {
    int row = blockIdx.x * 4 + (threadIdx.x >> 6);
    if (row >= rows) return;
    int lane = threadIdx.x & 63;
    const float* p = src + (size_t)row * rowlen;
    float s = 0.f;
    if (w) { for (int i = lane; i < rowlen; i += 64) s += p[i] * w[i]; }
    else   { for (int i = lane; i < rowlen; i += 64) s += p[i]; }
#pragma unroll
    for (int off = 32; off > 0; off >>= 1) s += __shfl_down(s, off, 64);
    if (lane == 0) dst[row] = s;
}

__global__ void k_init(unsigned int* cnt) {
    if (threadIdx.x < nL) cnt[threadIdx.x * 64] = 0u;
}

// C[m,n] = act( sum_k A[m,k]*B[k,n] + bias[n] ), 128x128 tile, BK=16, fp32
template<int ACT>
__global__ __launch_bounds__(256) void k_gemm(
    const float* __restrict__ A, int lda, long long sA,
    const float* __restrict__ Bm, int ldb, long long sB,
    const float* __restrict__ bias, long long sBias,
    float* __restrict__ C, int ldc, long long sC,
    int M, int N, int K)
{
    A  += (size_t)blockIdx.z * sA;
    Bm += (size_t)blockIdx.z * sB;
    C  += (size_t)blockIdx.z * sC;
    const float* biasp = bias ? bias + (size_t)blockIdx.z * sBias : nullptr;

    __shared__ __align__(16) float As[16][128];  // [k][m]
    __shared__ __align__(16) float Bs[16][128];  // [k][n]
    const int tid = threadIdx.x;
    const int tx = tid & 15, ty = tid >> 4;
    const int bm = blockIdx.y * 128, bn = blockIdx.x * 128;

    float acc[8][8];
#pragma unroll
    for (int i = 0; i < 8; ++i)
#pragma unroll
        for (int j = 0; j < 8; ++j) acc[i][j] = 0.f;

    const int arow = tid >> 1, ac8 = (tid & 1) * 8;
    const int brow = tid >> 4, bc8 = (tid & 15) * 8;

    for (int kt = 0; kt < K; kt += 16) {
        float4 a0 = *reinterpret_cast<const float4*>(A + (size_t)(bm + arow) * lda + kt + ac8);
        float4 a1 = *reinterpret_cast<const float4*>(A + (size_t)(bm + arow) * lda + kt + ac8 + 4);
        float4 b0 = *reinterpret_cast<const float4*>(Bm + (size_t)(kt + brow) * ldb + bn + bc8);
        float4 b1 = *reinterpret_cast<const float4*>(Bm + (size_t)(kt + brow) * ldb + bn + bc8 + 4);
        __syncthreads();
        As[ac8 + 0][arow] = a0.x; As[ac8 + 1][arow] = a0.y;
        As[ac8 + 2][arow] = a0.z; As[ac8 + 3][arow] = a0.w;
        As[ac8 + 4][arow] = a1.x; As[ac8 + 5][arow] = a1.y;
        As[ac8 + 6][arow] = a1.z; As[ac8 + 7][arow] = a1.w;
        *reinterpret_cast<float4*>(&Bs[brow][bc8]) = b0;
        *reinterpret_cast<float4*>(&Bs[brow][bc8 + 4]) = b1;
        __syncthreads();
#pragma unroll
        for (int kk = 0; kk < 16; ++kk) {
            float ar[8], br[8];
            *reinterpret_cast<float4*>(&ar[0]) = *reinterpret_cast<const float4*>(&As[kk][ty * 4]);
            *reinterpret_cast<float4*>(&ar[4]) = *reinterpret_cast<const float4*>(&As[kk][64 + ty * 4]);
            *reinterpret_cast<float4*>(&br[0]) = *reinterpret_cast<const float4*>(&Bs[kk][tx * 4]);
            *reinterpret_cast<float4*>(&br[4]) = *reinterpret_cast<const float4*>(&Bs[kk][64 + tx * 4]);
#pragma unroll
            for (int i = 0; i < 8; ++i)
#pragma unroll
                for (int j = 0; j < 8; ++j) acc[i][j] = fmaf(ar[i], br[j], acc[i][j]);
        }
    }
#pragma unroll
    for (int i = 0; i < 8; ++i) {
        int r = bm + (i >> 2) * 64 + ty * 4 + (i & 3);
#pragma unroll
        for (int jh = 0; jh < 2; ++jh) {
            int cb = bn + jh * 64 + tx * 4;
            float4 v = make_float4(acc[i][jh * 4 + 0], acc[i][jh * 4 + 1],
                                   acc[i][jh * 4 + 2], acc[i][jh * 4 + 3]);
            if (biasp) { v.x += biasp[cb]; v.y += biasp[cb + 1]; v.z += biasp[cb + 2]; v.w += biasp[cb + 3]; }
            if (ACT == 1) { v.x = gelu_f(v.x); v.y = gelu_f(v.y); v.z = gelu_f(v.z); v.w = gelu_f(v.w); }
            *reinterpret_cast<float4*>(C + (size_t)r * ldc + cb) = v;
        }
    }
}

// ---------------------------------------------------------------------------
// Distributed scan: 256 WGs = 8 layers x 32 column-chunks. Each WG owns 32
// proj-cols (16 a + 16 g => 16 state dims) for all 8 batches; weights live in
// LDS (fp32, loaded once). Per step: one cross-WG exchange of raw GLU output
// (v) + LN partial sums via global, guarded by a per-layer atomic barrier.
// vout holds RAW v; consumers reconstruct state via psum partials.
// ---------------------------------------------------------------------------
__global__ __launch_bounds__(256, 1) void k_scan2(
    const float* __restrict__ tokens,      // [B,T,L,D]
    const float* __restrict__ glu_w,       // [L,D,2D] fp32
    const float* __restrict__ glu_b,       // [L,2D]
    const float* __restrict__ sc_sum, const float* __restrict__ ii_sum,  // [L,D]
    const float* __restrict__ ln_glu_g, const float* __restrict__ ln_glu_b,
    const float* __restrict__ ln_state_g, const float* __restrict__ ln_state_b,
    float* __restrict__ vout,              // [B,T,L,D] raw v
    float* __restrict__ psum,              // [T,L,B,32,2] partial sums of v
    unsigned int* __restrict__ cnt)        // per-layer barrier counters
{
    const int l = blockIdx.x & 7;
    const int q = blockIdx.x >> 3;         // column chunk 0..31

    __shared__ __align__(16) float w_lds[128][32][4];  // 64 KB: [k/4][col][k%4]
    __shared__ __align__(16) float hn_lds[8][512];     // 16 KB
    __shared__ __align__(16) float red[8][8][32];      //  8 KB: [kc][b][col]
    __shared__ __align__(16) float s_par[6][512];      // 12 KB: sc,ii,gg,gb,sg,sb

    const int tid = threadIdx.x;

    for (int i = tid; i < nD; i += 256) {
        s_par[0][i] = sc_sum[l * nD + i];
        s_par[1][i] = ii_sum[l * nD + i];
        s_par[2][i] = ln_glu_g[i];   s_par[3][i] = ln_glu_b[i];
        s_par[4][i] = ln_state_g[i]; s_par[5][i] = ln_state_b[i];
    }
    {   // weight slice preload (once): w_lds[k>>2][c][k&3] = glu_w[l][k][gcol(c)]
        const int c = tid & 31;
        const int gcol = (c < 16) ? (q * 16 + c) : (512 + q * 16 + (c - 16));
        const float* wsrc = glu_w + (size_t)l * nD * (2 * nD) + gcol;
        for (int kk = tid >> 5; kk < nD; kk += 8)
            w_lds[kk >> 2][c][kk & 3] = wsrc[(size_t)kk * (2 * nD)];
    }

    const int ba = tid >> 5;    // phase A/C: batch
    const int ks = tid & 31;    // phase A: k-subchunk / phase C: col
    const int kc = tid >> 5;    // phase B: k-chunk
    const int c  = tid & 31;    // phase B: col
    const int gcolp = (ks < 16) ? (q * 16 + ks) : (512 + q * 16 + (ks - 16));
    const float bias_c = glu_b[l * (2 * nD) + gcolp];

    const size_t tok_tstride = (size_t)nL * nD;
    const float* tokbase = tokens + ((size_t)ba * nT) * tok_tstride + (size_t)l * nD;

    // prefetch token t=0 (k offsets ks*4 + 128*m -> coalesced per 32-lane group)
    float4 tokv[4];
#pragma unroll
    for (int m = 0; m < 4; ++m)
        tokv[m] = *reinterpret_cast<const float4*>(tokbase + ks * 4 + 128 * m);

    unsigned int* mycnt = cnt + l * 64;
    __syncthreads();

    for (int t = 0; t < nT; ++t) {
        if (t > 0) {
            if (tid == 0) {
                const unsigned int target = 32u * (unsigned int)t;
                while (__hip_atomic_load(mycnt, __ATOMIC_ACQUIRE,
                                         __HIP_MEMORY_SCOPE_AGENT) < target)
                    __builtin_amdgcn_s_sleep(1);
            }
            __syncthreads();
        }

        // ---- phase A: state(t-1) from raw v + partials; h; LN -> hn_lds ----
        float h[16];
        if (t > 0) {
            float2 p2 = *reinterpret_cast<const float2*>(
                psum + ((((size_t)(t - 1) * nL + l) * nB + ba) * 32 + ks) * 2);
            float S = p2.x, Q = p2.y;
#pragma unroll
            for (int o = 16; o > 0; o >>= 1) { S += __shfl_xor(S, o, 64); Q += __shfl_xor(Q, o, 64); }
            const float mv = S * (1.f / nD);
            const float iv = rsqrtf(Q * (1.f / nD) - mv * mv + 1e-5f);
            const float* vprev = vout + (((size_t)ba * nT + (t - 1)) * nL + l) * nD;
#pragma unroll
            for (int m = 0; m < 4; ++m) {
                const int k0 = ks * 4 + 128 * m;
                float4 v4  = *reinterpret_cast<const float4*>(vprev + k0);
                float4 sg4 = *reinterpret_cast<const float4*>(&s_par[4][k0]);
                float4 sb4 = *reinterpret_cast<const float4*>(&s_par[5][k0]);
                float4 sc4 = *reinterpret_cast<const float4*>(&s_par[0][k0]);
                float4 ii4 = *reinterpret_cast<const float4*>(&s_par[1][k0]);
                float st;
                st = (v4.x - mv) * iv * sg4.x + sb4.x; h[m * 4 + 0] = st * sc4.x + tokv[m].x * ii4.x;
                st = (v4.y - mv) * iv * sg4.y + sb4.y; h[m * 4 + 1] = st * sc4.y + tokv[m].y * ii4.y;
                st = (v4.z - mv) * iv * sg4.z + sb4.z; h[m * 4 + 2] = st * sc4.z + tokv[m].z * ii4.z;
                st = (v4.w - mv) * iv * sg4.w + sb4.w; h[m * 4 + 3] = st * sc4.w + tokv[m].w * ii4.w;
            }
        } else {
#pragma unroll
            for (int m = 0; m < 4; ++m) {
                const int k0 = ks * 4 + 128 * m;
                float4 ii4 = *reinterpret_cast<const float4*>(&s_par[1][k0]);
                h[m * 4 + 0] = tokv[m].x * ii4.x; h[m * 4 + 1] = tokv[m].y * ii4.y;
                h[m * 4 + 2] = tokv[m].z * ii4.z; h[m * 4 + 3] = tokv[m].w * ii4.w;
            }
        }
        float S = 0.f, Q = 0.f;
#pragma unroll
        for (int j = 0; j < 16; ++j) { S += h[j]; Q += h[j] * h[j]; }
#pragma unroll
        for (int o = 16; o > 0; o >>= 1) { S += __shfl_xor(S, o, 64); Q += __shfl_xor(Q, o, 64); }
        {
            const float mh = S * (1.f / nD);
            const float ih = rsqrtf(Q * (1.f / nD) - mh * mh + 1e-5f);
#pragma unroll
            for (int m = 0; m < 4; ++m) {
                const int k0 = ks * 4 + 128 * m;
                float4 gg4 = *reinterpret_cast<const float4*>(&s_par[2][k0]);
                float4 gb4 = *reinterpret_cast<const float4*>(&s_par[3][k0]);
                float4 o4;
                o4.x = (h[m * 4 + 0] - mh) * ih * gg4.x + gb4.x;
                o4.y = (h[m * 4 + 1] - mh) * ih * gg4.y + gb4.y;
                o4.z = (h[m * 4 + 2] - mh) * ih * gg4.z + gb4.z;
                o4.w = (h[m * 4 + 3] - mh) * ih * gg4.w + gb4.w;
                *reinterpret_cast<float4*>(&hn_lds[ba][k0]) = o4;
            }
        }
        // prefetch next token during matvec
        {
            const int tn = (t + 1 < nT) ? t + 1 : t;
#pragma unroll
            for (int m = 0; m < 4; ++m)
                tokv[m] = *reinterpret_cast<const float4*>(
                    tokbase + (size_t)tn * tok_tstride + ks * 4 + 128 * m);
        }
        __syncthreads();

        // ---- phase B: matvec from LDS: acc[b] over k in [kc*64, kc*64+64) ----
        float acc[8];
#pragma unroll
        for (int b = 0; b < 8; ++b) acc[b] = 0.f;
#pragma unroll
        for (int j4 = 0; j4 < 16; ++j4) {
            const int k4 = kc * 16 + j4;
            float4 w4 = *reinterpret_cast<const float4*>(&w_lds[k4][c][0]);
#pragma unroll
            for (int b = 0; b < 8; ++b) {
                float4 hn4 = *reinterpret_cast<const float4*>(&hn_lds[b][k4 * 4]);
                acc[b] = fmaf(w4.x, hn4.x, fmaf(w4.y, hn4.y,
                         fmaf(w4.z, hn4.z, fmaf(w4.w, hn4.w, acc[b]))));
            }
        }
#pragma unroll
        for (int b = 0; b < 8; ++b) red[kc][b][c] = acc[b];
        __syncthreads();

        // ---- phase C: split-k reduce, GLU, partial sums, exchange ----
        float proj = bias_c;
#pragma unroll
        for (int k2 = 0; k2 < 8; ++k2) proj += red[k2][ba][ks];
        const float g = __shfl_xor(proj, 16, 64);        // pair a<->g cols
        const float v = proj / (1.f + __expf(-g));
        float cs = (ks < 16) ? v : 0.f;
        float cq = (ks < 16) ? v * v : 0.f;
#pragma unroll
        for (int o = 16; o > 0; o >>= 1) { cs += __shfl_xor(cs, o, 64); cq += __shfl_xor(cq, o, 64); }
        if (ks < 16)
            vout[(((size_t)ba * nT + t) * nL + l) * nD + q * 16 + ks] = v;
        if (ks == 0)
            *reinterpret_cast<float2*>(
                psum + ((((size_t)t * nL + l) * nB + ba) * 32 + q) * 2) = make_float2(cs, cq);
        __threadfence();
        __syncthreads();
        if (tid == 0 && t + 1 < nT)
            __hip_atomic_fetch_add(mycnt, 1u, __ATOMIC_RELEASE, __HIP_MEMORY_SCOPE_AGENT);
    }
}

// y = LN_ff( LN_state(raw v) * os_sum[l] ); one wave per (b,t,l) row
__global__ __launch_bounds__(256) void k_y2(
    const float* __restrict__ vout, const float* __restrict__ psum,
    const float* __restrict__ os_sum,
    const float* __restrict__ ln_state_g, const float* __restrict__ ln_state_b,
    const float* __restrict__ fg, const float* __restrict__ fb,
    float* __restrict__ y)
{
    const int row = blockIdx.x * 4 + (threadIdx.x >> 6);   // over B*T*L
    const int lane = threadIdx.x & 63;
    const int l = row & 7;
    const int bt = row >> 3;
    const int t = bt & (nT - 1);
    const int b = bt >> 9;

    float2 p2 = *reinterpret_cast<const float2*>(
        psum + ((((size_t)t * nL + l) * nB + b) * 32 + (lane & 31)) * 2);
    float S = p2.x, Q = p2.y;
#pragma unroll
    for (int o = 16; o > 0; o >>= 1) { S += __shfl_xor(S, o, 64); Q += __shfl_xor(Q, o, 64); }
    const float mv = S * (1.f / nD);
    const float iv = rsqrtf(Q * (1.f / nD) - mv * mv + 1e-5f);

    const float* vp = vout + (size_t)row * nD;
    const float* op = os_sum + l * nD;
    const float* sg = ln_state_g, *sb = ln_state_b;
    const int base = lane * 8;
    float val[8];
    float s2 = 0.f, q2 = 0.f;
#pragma unroll
    for (int j = 0; j < 8; j += 4) {
        float4 v4 = *reinterpret_cast<const float4*>(vp + base + j);
        float4 o4 = *reinterpret_cast<const float4*>(op + base + j);
        float4 g4 = *reinterpret_cast<const float4*>(sg + base + j);
        float4 b4 = *reinterpret_cast<const float4*>(sb + base + j);
        val[j]     = ((v4.x - mv) * iv * g4.x + b4.x) * o4.x;
        val[j + 1] = ((v4.y - mv) * iv * g4.y + b4.y) * o4.y;
        val[j + 2] = ((v4.z - mv) * iv * g4.z + b4.z) * o4.z;
        val[j + 3] = ((v4.w - mv) * iv * g4.w + b4.w) * o4.w;
    }
#pragma unroll
    for (int j = 0; j < 8; ++j) { s2 += val[j]; q2 += val[j] * val[j]; }
#pragma unroll
    for (int o = 32; o > 0; o >>= 1) { s2 += __shfl_xor(s2, o, 64); q2 += __shfl_xor(q2, o, 64); }
    const float m2 = s2 * (1.f / nD);
    const float i2 = rsqrtf(q2 * (1.f / nD) - m2 * m2 + 1e-5f);
    const float* gp = fg + l * nD;
    const float* bp = fb + l * nD;
    float* yp = y + (size_t)row * nD;
#pragma unroll
    for (int j = 0; j < 8; j += 4) {
        float4 g4 = *reinterpret_cast<const float4*>(gp + base + j);
        float4 b4 = *reinterpret_cast<const float4*>(bp + base + j);
        float4 o;
        o.x = (val[j]     - m2) * i2 * g4.x + b4.x;
        o.y = (val[j + 1] - m2) * i2 * g4.y + b4.y;
        o.z = (val[j + 2] - m2) * i2 * g4.z + b4.z;
        o.w = (val[j + 3] - m2) * i2 * g4.w + b4.w;
        *reinterpret_cast<float4*>(yp + base + j) = o;
    }
}

// scores from h via w2a; softmax over L; scale h in place; store probs
__global__ __launch_bounds__(256) void k_scores(
    float* __restrict__ h, const float* __restrict__ w2a,
    const float* __restrict__ c2, const float* __restrict__ attn_b,
    float* __restrict__ scores)
{
    const int bt = blockIdx.x;
    const int tid = threadIdx.x, wid = tid >> 6, lane = tid & 63;
    __shared__ float slog[nL];
    float* hrow = h + (size_t)bt * nLD;
    for (int l = wid; l < nL; l += 4) {
        const float* hp = hrow + l * nD;
        const float* wp = w2a + l * nD;
        float s = 0.f;
        for (int i = lane; i < nD; i += 64) s += hp[i] * wp[i];
#pragma unroll
        for (int off = 32; off > 0; off >>= 1) s += __shfl_down(s, off, 64);
        if (lane == 0) slog[l] = s + c2[l] + attn_b[0];
    }
    __syncthreads();
    float mx = -1e30f;
#pragma unroll
    for (int l = 0; l < nL; ++l) mx = fmaxf(mx, slog[l]);
    float den = 0.f;
#pragma unroll
    for (int l = 0; l < nL; ++l) den += __expf(slog[l] - mx);
    float rden = 1.f / den;
#pragma unroll
    for (int it = 0; it < 4; ++it) {
        int idx = tid * 4 + it * 1024;
        int l = idx >> 9;
        float s = __expf(slog[l] - mx) * rden;
        float4 v = *reinterpret_cast<float4*>(hrow + idx);
        v.x *= s; v.y *= s; v.z *= s; v.w *= s;
        *reinterpret_cast<float4*>(hrow + idx) = v;
    }
    if (tid < nL) scores[bt * nL + tid] = __expf(slog[tid] - mx) * rden;
}

// out = LN( wbuf + sum_l s_l * ff_b2[l] ) with ln_emb params
__global__ __launch_bounds__(256) void k_final(
    const float* __restrict__ wbuf, const float* __restrict__ scores,
    const float* __restrict__ ff_b2, const float* __restrict__ g,
    const float* __restrict__ bvec, float* __restrict__ out)
{
    const int bt = blockIdx.x;
    const int tid = threadIdx.x;
    __shared__ float ssc[nL];
    __shared__ float red[8];
    if (tid < nL) ssc[tid] = scores[bt * nL + tid];
    __syncthreads();
    const int e0 = tid * 4;
    float4 w = *reinterpret_cast<const float4*>(wbuf + (size_t)bt * nE + e0);
#pragma unroll
    for (int l = 0; l < nL; ++l) {
        float s = ssc[l];
        float4 b2 = *reinterpret_cast<const float4*>(ff_b2 + l * nE + e0);
        w.x += s * b2.x; w.y += s * b2.y; w.z += s * b2.z; w.w += s * b2.w;
    }
    float sum = w.x + w.y + w.z + w.w;
    float sq = w.x * w.x + w.y * w.y + w.z * w.z + w.w * w.w;
    int wid = tid >> 6, lane = tid & 63;
#pragma unroll
    for (int off = 32; off > 0; off >>= 1) {
        sum += __shfl_down(sum, off, 64); sq += __shfl_down(sq, off, 64);
    }
    if (lane == 0) { red[wid] = sum; red[4 + wid] = sq; }
    __syncthreads();
    sum = red[0] + red[1] + red[2] + red[3];
    sq  = red[4] + red[5] + red[6] + red[7];
    float mean = sum * (1.f / nE);
    float inv = rsqrtf(sq * (1.f / nE) - mean * mean + 1e-5f);
    float4 g4 = *reinterpret_cast<const float4*>(g + e0);
    float4 b4 = *reinterpret_cast<const float4*>(bvec + e0);
    float4 o;
    o.x = (w.x - mean) * inv * g4.x + b4.x;
    o.y = (w.y - mean) * inv * g4.y + b4.y;
    o.z = (w.z - mean) * inv * g4.z + b4.z;
    o.w = (w.w - mean) * inv * g4.w + b4.w;
    *reinterpret_cast<float4*>(out + (size_t)bt * nE + e0) = o;
}

extern "C" void kernel_launch(void* const* d_in, const int* in_sizes, int n_in,
                              void* d_out, int out_size, void* d_ws, size_t ws_size,
                              hipStream_t stream) {
    (void)in_sizes; (void)n_in; (void)out_size; (void)ws_size;
    const float* emb            = (const float*)d_in[0];
    const float* state_control  = (const float*)d_in[1];
    const float* input_influence= (const float*)d_in[2];
    const float* output_shaper  = (const float*)d_in[3];
    const float* glu_w          = (const float*)d_in[4];
    const float* glu_b          = (const float*)d_in[5];
    const float* e2s_w          = (const float*)d_in[6];
    const float* e2s_b          = (const float*)d_in[7];
    const float* ln_glu_g       = (const float*)d_in[8];
    const float* ln_glu_b       = (const float*)d_in[9];
    const float* ln_state_g     = (const float*)d_in[10];
    const float* ln_state_b     = (const float*)d_in[11];
    const float* ln_emb_g       = (const float*)d_in[12];
    const float* ln_emb_b       = (const float*)d_in[13];
    const float* ff_ln_g        = (const float*)d_in[14];
    const float* ff_ln_b        = (const float*)d_in[15];
    const float* ff_w1          = (const float*)d_in[16];
    const float* ff_b1          = (const float*)d_in[17];
    const float* ff_w2          = (const float*)d_in[18];
    const float* ff_b2          = (const float*)d_in[19];
    const float* attn_w         = (const float*)d_in[20];
    const float* attn_b         = (const float*)d_in[21];

    // workspace layout (~137 MB)
    char* ws = (char*)d_ws;
    float* tokens = (float*)ws;  ws += (size_t)nBT * nLD * 4;       // 67 MB (later: y, then wbuf)
    float* vbuf   = (float*)ws;  ws += (size_t)nBT * nLD * 4;       // 67 MB raw v (later: h)
    float* psum   = (float*)ws;  ws += (size_t)nT * nL * nB * 32 * 2 * 4;  // 2 MB
    float* sc_sum = (float*)ws;  ws += nLD * 4;
    float* ii_sum = (float*)ws;  ws += nLD * 4;
    float* os_sum = (float*)ws;  ws += nLD * 4;
    float* w2a    = (float*)ws;  ws += nLD * 4;
    float* c2     = (float*)ws;  ws += 256;
    float* scores = (float*)ws;  ws += (size_t)nBT * nL * 4;
    unsigned int* cnt = (unsigned int*)ws; ws += nL * 64 * 4;
    float* wbuf = tokens;  // alias: tokens (y) dead after ff1 GEMM

    // precompute
    k_init<<<1, 64, 0, stream>>>(cnt);
    k_wdot<<<1024, 256, 0, stream>>>(state_control, nullptr, sc_sum, nLD, nD);
    k_wdot<<<1024, 256, 0, stream>>>(input_influence, nullptr, ii_sum, nLD, nD);
    k_wdot<<<1024, 256, 0, stream>>>(output_shaper, nullptr, os_sum, nLD, nD);
    k_wdot<<<1024, 256, 0, stream>>>(ff_w2, attn_w, w2a, nLD, nE);
    k_wdot<<<2, 256, 0, stream>>>(ff_b2, attn_w, c2, nL, nE);

    // tokens = emb @ e2s_w + e2s_b   [4096 x 4096], K=1024
    k_gemm<0><<<dim3(32, 32, 1), 256, 0, stream>>>(
        emb, nE, 0, e2s_w, nLD, 0, e2s_b, 0, tokens, nLD, 0, nBT, nLD, nE);

    // distributed recurrent scan -> raw v + partials
    k_scan2<<<256, 256, 0, stream>>>(tokens, glu_w, glu_b, sc_sum, ii_sum,
                                     ln_glu_g, ln_glu_b, ln_state_g, ln_state_b,
                                     vbuf, psum, cnt);

    // y = LN_ff(LN_state(v) * os_sum)  (into tokens buffer)
    k_y2<<<nBT * nL / 4, 256, 0, stream>>>(vbuf, psum, os_sum,
                                           ln_state_g, ln_state_b,
                                           ff_ln_g, ff_ln_b, tokens);

    // h = GELU(y @ ff_w1 + ff_b1), per-layer batched  (into vbuf)
    k_gemm<1><<<dim3(4, 32, 8), 256, 0, stream>>>(
        tokens, nLD, nD, ff_w1, nD, (long long)nD * nD, ff_b1, nD,
        vbuf, nLD, nD, nBT, nD, nD);

    // scores + scale h in place
    k_scores<<<nBT, 256, 0, stream>>>(vbuf, w2a, c2, attn_b, scores);

    // weighted = (s*h) @ W2cat   [4096 x 1024], K=4096  (into wbuf=tokens)
    k_gemm<0><<<dim3(8, 32, 1), 256, 0, stream>>>(
        vbuf, nLD, 0, ff_w2, nE, 0, nullptr, 0, wbuf, nE, 0, nBT, nE, nLD);

    // out = LN(weighted + sum_l s_l*ff_b2[l])
    k_final<<<nBT, 256, 0, stream>>>(wbuf, scores, ff_b2, ln_emb_g, ln_emb_b, (float*)d_out);
}

// Round 3
// 6999.993 us; speedup vs baseline: 2.3785x; 2.3785x over previous
//
#include <hip/hip_runtime.h>
#include <hip/hip_bf16.h>
#include <math.h>

// Fixed problem dims
static constexpr int nB = 8, nT = 512, nE = 1024, nL = 8, nD = 512;
static constexpr int nBT = nB * nT;   // 4096 rows (b,t)
static constexpr int nLD = nL * nD;   // 4096

__device__ __forceinline__ unsigned short f2bf(float f) {
    unsigned int u = __float_as_uint(f);
    return (unsigned short)((u + 0x7fffu + ((u >> 16) & 1u)) >> 16);  // RNE
}
__device__ __forceinline__ float gelu_f(float x) {
    return 0.5f * x * (1.0f + erff(x * 0.70710678118654752f));  // exact GELU
}
// acc += w0*h0 + w1*h1, operands packed bf16 pairs in uints (manual unpack --
// safe everywhere; v_dot2_f32_bf16 candidate for a later round)
__device__ __forceinline__ float dot2bf(unsigned int w, unsigned int h, float acc) {
    float w0 = __uint_as_float(w << 16), w1 = __uint_as_float(w & 0xffff0000u);
    float h0 = __uint_as_float(h << 16), h1 = __uint_as_float(h & 0xffff0000u);
    return fmaf(w1, h1, fmaf(w0, h0, acc));
}

// dst[r] = sum_i src[r,i] * (w ? w[i] : 1)
__global__ __launch_bounds__(256) void k_wdot(const float* __restrict__ src,
                                              const float* __restrict__ w,
                                              float* __restrict__ dst,
                                              int rows, int rowlen) {
    int row = blockIdx.x * 4 + (threadIdx.x >> 6);
    if (row >= rows) return;
    int lane = threadIdx.x & 63;
    const float* p = src + (size_t)row * rowlen;
    float s = 0.f;
    if (w) { for (int i = lane; i < rowlen; i += 64) s += p[i] * w[i]; }
    else   { for (int i = lane; i < rowlen; i += 64) s += p[i]; }
#pragma unroll
    for (int off = 32; off > 0; off >>= 1) s += __shfl_down(s, off, 64);
    if (lane == 0) dst[row] = s;
}

// pack glu_w rows (2k2, 2k2+1) into bf16-pair uints: wpk[l][k2][c]
__global__ __launch_bounds__(256) void k_pack(const float* __restrict__ src,
                                              unsigned int* __restrict__ dst) {
    const int lk = blockIdx.x;            // l*256 + k2  (2048 blocks)
    const int c4 = threadIdx.x * 4;       // 256 threads x 4 cols
    const float* r0 = src + (size_t)lk * 2 * 1024;
    const float* r1 = r0 + 1024;
    float4 a = *reinterpret_cast<const float4*>(r0 + c4);
    float4 b = *reinterpret_cast<const float4*>(r1 + c4);
    uint4 o;
    o.x = (unsigned)f2bf(a.x) | ((unsigned)f2bf(b.x) << 16);
    o.y = (unsigned)f2bf(a.y) | ((unsigned)f2bf(b.y) << 16);
    o.z = (unsigned)f2bf(a.z) | ((unsigned)f2bf(b.z) << 16);
    o.w = (unsigned)f2bf(a.w) | ((unsigned)f2bf(b.w) << 16);
    *reinterpret_cast<uint4*>(dst + (size_t)lk * 1024 + c4) = o;
}

// C[m,n] = act( sum_k A[m,k]*B[k,n] + bias[n] ), 128x128 tile, BK=16, fp32
template<int ACT>
__global__ __launch_bounds__(256) void k_gemm(
    const float* __restrict__ A, int lda, long long sA,
    const float* __restrict__ Bm, int ldb, long long sB,
    const float* __restrict__ bias, long long sBias,
    float* __restrict__ C, int ldc, long long sC,
    int M, int N, int K)
{
    A  += (size_t)blockIdx.z * sA;
    Bm += (size_t)blockIdx.z * sB;
    C  += (size_t)blockIdx.z * sC;
    const float* biasp = bias ? bias + (size_t)blockIdx.z * sBias : nullptr;

    __shared__ __align__(16) float As[16][128];  // [k][m]
    __shared__ __align__(16) float Bs[16][128];  // [k][n]
    const int tid = threadIdx.x;
    const int tx = tid & 15, ty = tid >> 4;
    const int bm = blockIdx.y * 128, bn = blockIdx.x * 128;

    float acc[8][8];
#pragma unroll
    for (int i = 0; i < 8; ++i)
#pragma unroll
        for (int j = 0; j < 8; ++j) acc[i][j] = 0.f;

    const int arow = tid >> 1, ac8 = (tid & 1) * 8;
    const int brow = tid >> 4, bc8 = (tid & 15) * 8;

    for (int kt = 0; kt < K; kt += 16) {
        float4 a0 = *reinterpret_cast<const float4*>(A + (size_t)(bm + arow) * lda + kt + ac8);
        float4 a1 = *reinterpret_cast<const float4*>(A + (size_t)(bm + arow) * lda + kt + ac8 + 4);
        float4 b0 = *reinterpret_cast<const float4*>(Bm + (size_t)(kt + brow) * ldb + bn + bc8);
        float4 b1 = *reinterpret_cast<const float4*>(Bm + (size_t)(kt + brow) * ldb + bn + bc8 + 4);
        __syncthreads();
        As[ac8 + 0][arow] = a0.x; As[ac8 + 1][arow] = a0.y;
        As[ac8 + 2][arow] = a0.z; As[ac8 + 3][arow] = a0.w;
        As[ac8 + 4][arow] = a1.x; As[ac8 + 5][arow] = a1.y;
        As[ac8 + 6][arow] = a1.z; As[ac8 + 7][arow] = a1.w;
        *reinterpret_cast<float4*>(&Bs[brow][bc8]) = b0;
        *reinterpret_cast<float4*>(&Bs[brow][bc8 + 4]) = b1;
        __syncthreads();
#pragma unroll
        for (int kk = 0; kk < 16; ++kk) {
            float ar[8], br[8];
            *reinterpret_cast<float4*>(&ar[0]) = *reinterpret_cast<const float4*>(&As[kk][ty * 4]);
            *reinterpret_cast<float4*>(&ar[4]) = *reinterpret_cast<const float4*>(&As[kk][64 + ty * 4]);
            *reinterpret_cast<float4*>(&br[0]) = *reinterpret_cast<const float4*>(&Bs[kk][tx * 4]);
            *reinterpret_cast<float4*>(&br[4]) = *reinterpret_cast<const float4*>(&Bs[kk][64 + tx * 4]);
#pragma unroll
            for (int i = 0; i < 8; ++i)
#pragma unroll
                for (int j = 0; j < 8; ++j) acc[i][j] = fmaf(ar[i], br[j], acc[i][j]);
        }
    }
#pragma unroll
    for (int i = 0; i < 8; ++i) {
        int r = bm + (i >> 2) * 64 + ty * 4 + (i & 3);
#pragma unroll
        for (int jh = 0; jh < 2; ++jh) {
            int cb = bn + jh * 64 + tx * 4;
            float4 v = make_float4(acc[i][jh * 4 + 0], acc[i][jh * 4 + 1],
                                   acc[i][jh * 4 + 2], acc[i][jh * 4 + 3]);
            if (biasp) { v.x += biasp[cb]; v.y += biasp[cb + 1]; v.z += biasp[cb + 2]; v.w += biasp[cb + 3]; }
            if (ACT == 1) { v.x = gelu_f(v.x); v.y = gelu_f(v.y); v.z = gelu_f(v.z); v.w = gelu_f(v.w); }
            *reinterpret_cast<float4*>(C + (size_t)r * ldc + cb) = v;
        }
    }
}

// ---------------------------------------------------------------------------
// Scan: one WG (512 threads, 8 waves) per (b,l) chain. No cross-WG sync.
// Weights stream from L2 as bf16 k-pair uints with 16-deep uint4 pipelining
// (128 KB in flight/CU). hn as packed bf16 pairs in LDS (broadcast reads).
// State carried in registers; per-dim params in registers.
// ---------------------------------------------------------------------------
__global__ __launch_bounds__(512, 1) void k_scan3(
    const float* __restrict__ tokens,       // [B,T,L,D]
    const unsigned int* __restrict__ wpk,   // [L,256,1024] packed bf16 pairs
    const float* __restrict__ glu_b,        // [L,2D]
    const float* __restrict__ sc_sum, const float* __restrict__ ii_sum,  // [L,D]
    const float* __restrict__ ln_glu_g, const float* __restrict__ ln_glu_b,
    const float* __restrict__ ln_state_g, const float* __restrict__ ln_state_b,
    float* __restrict__ states)             // [B,T,L,D]
{
    const int l = blockIdx.x & 7;           // blockIdx%8 = layer -> same XCD L2
    const int b = blockIdx.x >> 3;
    const int tid = threadIdx.x;            // 0..511, owns state dim d = tid
    const int lane = tid & 63, wid = tid >> 6;

    __shared__ unsigned int hn_pk[256];     // (hn[2k],hn[2k+1]) bf16 pairs
    __shared__ __align__(16) float red[2][1024];
    __shared__ float wred[32];

    // per-thread (per-dim) parameters in registers
    const float p_sc = sc_sum[l * nD + tid];
    const float p_ii = ii_sum[l * nD + tid];
    const float p_gg = ln_glu_g[tid],   p_gb = ln_glu_b[tid];
    const float p_sg = ln_state_g[tid], p_sb = ln_state_b[tid];
    const float p_ba = glu_b[l * 1024 + tid];        // a-col bias
    const float p_bg = glu_b[l * 1024 + 512 + tid];  // g-col bias

    const int half = tid >> 8;              // K-split: waves 0-3 / 4-7
    const int cg = tid & 255;               // owns proj cols 4cg..4cg+3
    const unsigned int* wp = wpk + (size_t)l * 256 * 1024
                                 + (size_t)half * 128 * 1024 + cg * 4;

    const float* tokp = tokens + (((size_t)b * nT) * nL + l) * nD + tid;
    float state = 0.f;
    float tok = tokp[0];

    for (int t = 0; t < nT; ++t) {
        // ---- phase A: h = state*sc + tok*ii ; LN -> hn (bf16 pairs in LDS)
        float h = state * p_sc + tok * p_ii;
        float s = h, q = h * h;
#pragma unroll
        for (int o = 32; o > 0; o >>= 1) { s += __shfl_xor(s, o, 64); q += __shfl_xor(q, o, 64); }
        if (lane == 0) { wred[wid] = s; wred[8 + wid] = q; }
        __syncthreads();
        s = 0.f; q = 0.f;
#pragma unroll
        for (int i = 0; i < 8; ++i) { s += wred[i]; q += wred[8 + i]; }
        float mean = s * (1.f / nD);
        float inv = rsqrtf(q * (1.f / nD) - mean * mean + 1e-5f);
        float hn = (h - mean) * inv * p_gg + p_gb;
        float hn_o = __shfl_xor(hn, 1, 64);
        if (!(tid & 1))
            hn_pk[tid >> 1] = (unsigned)f2bf(hn) | ((unsigned)f2bf(hn_o) << 16);
        __syncthreads();

        // prefetch next token during matvec
        if (t + 1 < nT) tok = tokp[(size_t)(t + 1) * nLD];

        // ---- phase B: matvec, 16-deep pipelined weight loads
        float4 acc = make_float4(0.f, 0.f, 0.f, 0.f);
        const unsigned int* hbase = &hn_pk[half * 128];
        for (int kb = 0; kb < 128; kb += 16) {
            uint4 wv[16];
#pragma unroll
            for (int i = 0; i < 16; ++i)
                wv[i] = *reinterpret_cast<const uint4*>(wp + (size_t)(kb + i) * 1024);
#pragma unroll
            for (int i = 0; i < 16; ++i) {
                const unsigned hp = hbase[kb + i];
                acc.x = dot2bf(wv[i].x, hp, acc.x);
                acc.y = dot2bf(wv[i].y, hp, acc.y);
                acc.z = dot2bf(wv[i].z, hp, acc.z);
                acc.w = dot2bf(wv[i].w, hp, acc.w);
            }
        }
        *reinterpret_cast<float4*>(&red[half][cg * 4]) = acc;
        __syncthreads();

        // ---- phase C: combine split-K, GLU, LN -> new state (in register)
        float a = red[0][tid] + red[1][tid] + p_ba;
        float g = red[0][tid + 512] + red[1][tid + 512] + p_bg;
        float v = a / (1.f + __expf(-g));
        s = v; q = v * v;
#pragma unroll
        for (int o = 32; o > 0; o >>= 1) { s += __shfl_xor(s, o, 64); q += __shfl_xor(q, o, 64); }
        if (lane == 0) { wred[16 + wid] = s; wred[24 + wid] = q; }
        __syncthreads();
        s = 0.f; q = 0.f;
#pragma unroll
        for (int i = 0; i < 8; ++i) { s += wred[16 + i]; q += wred[24 + i]; }
        mean = s * (1.f / nD);
        inv = rsqrtf(q * (1.f / nD) - mean * mean + 1e-5f);
        state = (v - mean) * inv * p_sg + p_sb;
        states[(((size_t)b * nT + t) * nL + l) * nD + tid] = state;
    }
}

// y = LN(states * os_sum[l]) with ff_ln params; one wave per row
__global__ __launch_bounds__(256) void k_y(
    const float* __restrict__ states, const float* __restrict__ os_sum,
    const float* __restrict__ fg, const float* __restrict__ fb,
    float* __restrict__ y)
{
    const int row = blockIdx.x * 4 + (threadIdx.x >> 6);
    const int lane = threadIdx.x & 63;
    const int l = row & 7;
    const float* sp = states + (size_t)row * nD;
    const float* op = os_sum + l * nD;
    const int base = lane * 8;
    float v[8];
    float sum = 0.f, sq = 0.f;
#pragma unroll
    for (int j = 0; j < 8; j += 4) {
        float4 s4 = *reinterpret_cast<const float4*>(sp + base + j);
        float4 o4 = *reinterpret_cast<const float4*>(op + base + j);
        v[j] = s4.x * o4.x; v[j + 1] = s4.y * o4.y; v[j + 2] = s4.z * o4.z; v[j + 3] = s4.w * o4.w;
    }
#pragma unroll
    for (int j = 0; j < 8; ++j) { sum += v[j]; sq += v[j] * v[j]; }
#pragma unroll
    for (int off = 32; off > 0; off >>= 1) {
        sum += __shfl_xor(sum, off, 64); sq += __shfl_xor(sq, off, 64);
    }
    float mean = sum * (1.f / nD);
    float inv = rsqrtf(sq * (1.f / nD) - mean * mean + 1e-5f);
    const float* gp = fg + l * nD;
    const float* bp = fb + l * nD;
    float* yp = y + (size_t)row * nD;
#pragma unroll
    for (int j = 0; j < 8; j += 4) {
        float4 g4 = *reinterpret_cast<const float4*>(gp + base + j);
        float4 b4 = *reinterpret_cast<const float4*>(bp + base + j);
        float4 o;
        o.x = (v[j]     - mean) * inv * g4.x + b4.x;
        o.y = (v[j + 1] - mean) * inv * g4.y + b4.y;
        o.z = (v[j + 2] - mean) * inv * g4.z + b4.z;
        o.w = (v[j + 3] - mean) * inv * g4.w + b4.w;
        *reinterpret_cast<float4*>(yp + base + j) = o;
    }
}

// scores from h via w2a; softmax over L; scale h in place; store probs
__global__ __launch_bounds__(256) void k_scores(
    float* __restrict__ h, const float* __restrict__ w2a,
    const float* __restrict__ c2, const float* __restrict__ attn_b,
    float* __restrict__ scores)
{
    const int bt = blockIdx.x;
    const int tid = threadIdx.x, wid = tid >> 6, lane = tid & 63;
    __shared__ float slog[nL];
    float* hrow = h + (size_t)bt * nLD;
    for (int l = wid; l < nL; l += 4) {
        const float* hp = hrow + l * nD;
        const float* wp = w2a + l * nD;
        float s = 0.f;
        for (int i = lane; i < nD; i += 64) s += hp[i] * wp[i];
#pragma unroll
        for (int off = 32; off > 0; off >>= 1) s += __shfl_down(s, off, 64);
        if (lane == 0) slog[l] = s + c2[l] + attn_b[0];
    }
    __syncthreads();
    float mx = -1e30f;
#pragma unroll
    for (int l = 0; l < nL; ++l) mx = fmaxf(mx, slog[l]);
    float den = 0.f;
#pragma unroll
    for (int l = 0; l < nL; ++l) den += __expf(slog[l] - mx);
    float rden = 1.f / den;
#pragma unroll
    for (int it = 0; it < 4; ++it) {
        int idx = tid * 4 + it * 1024;
        int l = idx >> 9;
        float s = __expf(slog[l] - mx) * rden;
        float4 v = *reinterpret_cast<float4*>(hrow + idx);
        v.x *= s; v.y *= s; v.z *= s; v.w *= s;
        *reinterpret_cast<float4*>(hrow + idx) = v;
    }
    if (tid < nL) scores[bt * nL + tid] = __expf(slog[tid] - mx) * rden;
}

// out = LN( wbuf + sum_l s_l * ff_b2[l] ) with ln_emb params
__global__ __launch_bounds__(256) void k_final(
    const float* __restrict__ wbuf, const float* __restrict__ scores,
    const float* __restrict__ ff_b2, const float* __restrict__ g,
    const float* __restrict__ bvec, float* __restrict__ out)
{
    const int bt = blockIdx.x;
    const int tid = threadIdx.x;
    __shared__ float ssc[nL];
    __shared__ float red[8];
    if (tid < nL) ssc[tid] = scores[bt * nL + tid];
    __syncthreads();
    const int e0 = tid * 4;
    float4 w = *reinterpret_cast<const float4*>(wbuf + (size_t)bt * nE + e0);
#pragma unroll
    for (int l = 0; l < nL; ++l) {
        float s = ssc[l];
        float4 b2 = *reinterpret_cast<const float4*>(ff_b2 + l * nE + e0);
        w.x += s * b2.x; w.y += s * b2.y; w.z += s * b2.z; w.w += s * b2.w;
    }
    float sum = w.x + w.y + w.z + w.w;
    float sq = w.x * w.x + w.y * w.y + w.z * w.z + w.w * w.w;
    int wid = tid >> 6, lane = tid & 63;
#pragma unroll
    for (int off = 32; off > 0; off >>= 1) {
        sum += __shfl_down(sum, off, 64); sq += __shfl_down(sq, off, 64);
    }
    if (lane == 0) { red[wid] = sum; red[4 + wid] = sq; }
    __syncthreads();
    sum = red[0] + red[1] + red[2] + red[3];
    sq  = red[4] + red[5] + red[6] + red[7];
    float mean = sum * (1.f / nE);
    float inv = rsqrtf(sq * (1.f / nE) - mean * mean + 1e-5f);
    float4 g4 = *reinterpret_cast<const float4*>(g + e0);
    float4 b4 = *reinterpret_cast<const float4*>(bvec + e0);
    float4 o;
    o.x = (w.x - mean) * inv * g4.x + b4.x;
    o.y = (w.y - mean) * inv * g4.y + b4.y;
    o.z = (w.z - mean) * inv * g4.z + b4.z;
    o.w = (w.w - mean) * inv * g4.w + b4.w;
    *reinterpret_cast<float4*>(out + (size_t)bt * nE + e0) = o;
}

extern "C" void kernel_launch(void* const* d_in, const int* in_sizes, int n_in,
                              void* d_out, int out_size, void* d_ws, size_t ws_size,
                              hipStream_t stream) {
    (void)in_sizes; (void)n_in; (void)out_size; (void)ws_size;
    const float* emb            = (const float*)d_in[0];
    const float* state_control  = (const float*)d_in[1];
    const float* input_influence= (const float*)d_in[2];
    const float* output_shaper  = (const float*)d_in[3];
    const float* glu_w          = (const float*)d_in[4];
    const float* glu_b          = (const float*)d_in[5];
    const float* e2s_w          = (const float*)d_in[6];
    const float* e2s_b          = (const float*)d_in[7];
    const float* ln_glu_g       = (const float*)d_in[8];
    const float* ln_glu_b       = (const float*)d_in[9];
    const float* ln_state_g     = (const float*)d_in[10];
    const float* ln_state_b     = (const float*)d_in[11];
    const float* ln_emb_g       = (const float*)d_in[12];
    const float* ln_emb_b       = (const float*)d_in[13];
    const float* ff_ln_g        = (const float*)d_in[14];
    const float* ff_ln_b        = (const float*)d_in[15];
    const float* ff_w1          = (const float*)d_in[16];
    const float* ff_b1          = (const float*)d_in[17];
    const float* ff_w2          = (const float*)d_in[18];
    const float* ff_b2          = (const float*)d_in[19];
    const float* attn_w         = (const float*)d_in[20];
    const float* attn_b         = (const float*)d_in[21];

    // workspace layout (~143 MB)
    char* ws = (char*)d_ws;
    float* tokens = (float*)ws;  ws += (size_t)nBT * nLD * 4;       // 67 MB (later: y, then wbuf)
    float* states = (float*)ws;  ws += (size_t)nBT * nLD * 4;       // 67 MB (later: h)
    unsigned int* wpk = (unsigned int*)ws; ws += (size_t)nL * 256 * 1024 * 4;  // 8.4 MB
    float* sc_sum = (float*)ws;  ws += nLD * 4;
    float* ii_sum = (float*)ws;  ws += nLD * 4;
    float* os_sum = (float*)ws;  ws += nLD * 4;
    float* w2a    = (float*)ws;  ws += nLD * 4;
    float* c2     = (float*)ws;  ws += 256;
    float* scores = (float*)ws;  ws += (size_t)nBT * nL * 4;
    float* wbuf = tokens;  // alias: tokens (y) dead after ff1 GEMM

    // precompute
    k_pack<<<nL * 256, 256, 0, stream>>>(glu_w, wpk);
    k_wdot<<<1024, 256, 0, stream>>>(state_control, nullptr, sc_sum, nLD, nD);
    k_wdot<<<1024, 256, 0, stream>>>(input_influence, nullptr, ii_sum, nLD, nD);
    k_wdot<<<1024, 256, 0, stream>>>(output_shaper, nullptr, os_sum, nLD, nD);
    k_wdot<<<1024, 256, 0, stream>>>(ff_w2, attn_w, w2a, nLD, nE);
    k_wdot<<<2, 256, 0, stream>>>(ff_b2, attn_w, c2, nL, nE);

    // tokens = emb @ e2s_w + e2s_b   [4096 x 4096], K=1024
    k_gemm<0><<<dim3(32, 32, 1), 256, 0, stream>>>(
        emb, nE, 0, e2s_w, nLD, 0, e2s_b, 0, tokens, nLD, 0, nBT, nLD, nE);

    // recurrent scan -> states
    k_scan3<<<64, 512, 0, stream>>>(tokens, wpk, glu_b, sc_sum, ii_sum,
                                    ln_glu_g, ln_glu_b, ln_state_g, ln_state_b, states);

    // y = LN(states * os_sum)  (into tokens buffer)
    k_y<<<nBT * nL / 4, 256, 0, stream>>>(states, os_sum, ff_ln_g, ff_ln_b, tokens);

    // h = GELU(y @ ff_w1 + ff_b1), per-layer batched  (into states buffer)
    k_gemm<1><<<dim3(4, 32, 8), 256, 0, stream>>>(
        tokens, nLD, nD, ff_w1, nD, (long long)nD * nD, ff_b1, nD,
        states, nLD, nD, nBT, nD, nD);

    // scores + scale h in place
    k_scores<<<nBT, 256, 0, stream>>>(states, w2a, c2, attn_b, scores);

    // weighted = (s*h) @ W2cat   [4096 x 1024], K=4096  (into wbuf=tokens)
    k_gemm<0><<<dim3(8, 32, 1), 256, 0, stream>>>(
        states, nLD, 0, ff_w2, nE, 0, nullptr, 0, wbuf, nE, 0, nBT, nE, nLD);

    // out = LN(weighted + sum_l s_l*ff_b2[l])
    k_final<<<nBT, 256, 0, stream>>>(wbuf, scores, ff_b2, ln_emb_g, ln_emb_b, (float*)d_out);
}

// Round 5
// 4038.828 us; speedup vs baseline: 4.1223x; 1.7332x over previous
//
#include <hip/hip_runtime.h>
#include <hip/hip_bf16.h>
#include <math.h>

// Fixed problem dims
static constexpr int nB = 8, nT = 512, nE = 1024, nL = 8, nD = 512;
static constexpr int nBT = nB * nT;   // 4096 rows (b,t)
static constexpr int nLD = nL * nD;   // 4096

typedef __attribute__((ext_vector_type(8))) short short8v;  // 8 bf16 (4 VGPRs)
typedef __attribute__((ext_vector_type(4))) float f32x4;

__device__ __forceinline__ unsigned short f2bf(float f) {
    unsigned int u = __float_as_uint(f);
    return (unsigned short)((u + 0x7fffu + ((u >> 16) & 1u)) >> 16);  // RNE
}
__device__ __forceinline__ float gelu_f(float x) {
    return 0.5f * x * (1.0f + erff(x * 0.70710678118654752f));  // exact GELU
}

// dst[r] = sum_i src[r,i] * (w ? w[i] : 1)
__global__ __launch_bounds__(256) void k_wdot(const float* __restrict__ src,
                                              const float* __restrict__ w,
                                              float* __restrict__ dst,
                                              int rows, int rowlen) {
    int row = blockIdx.x * 4 + (threadIdx.x >> 6);
    if (row >= rows) return;
    int lane = threadIdx.x & 63;
    const float* p = src + (size_t)row * rowlen;
    float s = 0.f;
    if (w) { for (int i = lane; i < rowlen; i += 64) s += p[i] * w[i]; }
    else   { for (int i = lane; i < rowlen; i += 64) s += p[i]; }
#pragma unroll
    for (int off = 32; off > 0; off >>= 1) s += __shfl_down(s, off, 64);
    if (lane == 0) dst[row] = s;
}

__global__ void k_init(unsigned int* f) {
    int i = blockIdx.x * 256 + threadIdx.x;
    if (i < nL * 8 * 16) f[i] = 0u;
}

// Pack glu_w into MFMA B-fragment layout, bf16 pairs:
// dst[((l*8+q)*8+w)*16+kt][lane] = uint4 of pairs p: k = 32kt+8*(lane>>4)+2p(+1),
// col = colmap(q,w,lane&15)
__global__ __launch_bounds__(256) void k_pack2(const float* __restrict__ src,
                                               uint4* __restrict__ dst) {
    const int blk = blockIdx.x;            // l*64 + q*8 + w   (512 blocks)
    const int w = blk & 7, q = (blk >> 3) & 7, l = blk >> 6;
    const float* wl = src + (size_t)l * nD * 1024;
    for (int i = threadIdx.x; i < 16 * 64; i += 256) {
        const int kt = i >> 6, ln = i & 63;
        const int j = ln & 15, g = ln >> 4;
        const int col = (w < 4) ? (q * 64 + w * 16 + j)
                                : (512 + q * 64 + (w - 4) * 16 + j);
        const int k0 = 32 * kt + 8 * g;
        unsigned pr[4];
#pragma unroll
        for (int p = 0; p < 4; ++p) {
            float a = wl[(size_t)(k0 + 2 * p) * 1024 + col];
            float c = wl[(size_t)(k0 + 2 * p + 1) * 1024 + col];
            pr[p] = (unsigned)f2bf(a) | ((unsigned)f2bf(c) << 16);
        }
        dst[((((size_t)l * 8 + q) * 8 + w) * 16 + kt) * 64 + ln] =
            make_uint4(pr[0], pr[1], pr[2], pr[3]);
    }
}

// C[m,n] = act( sum_k A[m,k]*B[k,n] + bias[n] ), 128x128 tile, BK=16, fp32
template<int ACT>
__global__ __launch_bounds__(256) void k_gemm(
    const float* __restrict__ A, int lda, long long sA,
    const float* __restrict__ Bm, int ldb, long long sB,
    const float* __restrict__ bias, long long sBias,
    float* __restrict__ C, int ldc, long long sC,
    int M, int N, int K)
{
    A  += (size_t)blockIdx.z * sA;
    Bm += (size_t)blockIdx.z * sB;
    C  += (size_t)blockIdx.z * sC;
    const float* biasp = bias ? bias + (size_t)blockIdx.z * sBias : nullptr;

    __shared__ __align__(16) float As[16][128];
    __shared__ __align__(16) float Bs[16][128];
    const int tid = threadIdx.x;
    const int tx = tid & 15, ty = tid >> 4;
    const int bm = blockIdx.y * 128, bn = blockIdx.x * 128;

    float acc[8][8];
#pragma unroll
    for (int i = 0; i < 8; ++i)
#pragma unroll
        for (int j = 0; j < 8; ++j) acc[i][j] = 0.f;

    const int arow = tid >> 1, ac8 = (tid & 1) * 8;
    const int brow = tid >> 4, bc8 = (tid & 15) * 8;

    for (int kt = 0; kt < K; kt += 16) {
        float4 a0 = *reinterpret_cast<const float4*>(A + (size_t)(bm + arow) * lda + kt + ac8);
        float4 a1 = *reinterpret_cast<const float4*>(A + (size_t)(bm + arow) * lda + kt + ac8 + 4);
        float4 b0 = *reinterpret_cast<const float4*>(Bm + (size_t)(kt + brow) * ldb + bn + bc8);
        float4 b1 = *reinterpret_cast<const float4*>(Bm + (size_t)(kt + brow) * ldb + bn + bc8 + 4);
        __syncthreads();
        As[ac8 + 0][arow] = a0.x; As[ac8 + 1][arow] = a0.y;
        As[ac8 + 2][arow] = a0.z; As[ac8 + 3][arow] = a0.w;
        As[ac8 + 4][arow] = a1.x; As[ac8 + 5][arow] = a1.y;
        As[ac8 + 6][arow] = a1.z; As[ac8 + 7][arow] = a1.w;
        *reinterpret_cast<float4*>(&Bs[brow][bc8]) = b0;
        *reinterpret_cast<float4*>(&Bs[brow][bc8 + 4]) = b1;
        __syncthreads();
#pragma unroll
        for (int kk = 0; kk < 16; ++kk) {
            float ar[8], br[8];
            *reinterpret_cast<float4*>(&ar[0]) = *reinterpret_cast<const float4*>(&As[kk][ty * 4]);
            *reinterpret_cast<float4*>(&ar[4]) = *reinterpret_cast<const float4*>(&As[kk][64 + ty * 4]);
            *reinterpret_cast<float4*>(&br[0]) = *reinterpret_cast<const float4*>(&Bs[kk][tx * 4]);
            *reinterpret_cast<float4*>(&br[4]) = *reinterpret_cast<const float4*>(&Bs[kk][64 + tx * 4]);
#pragma unroll
            for (int i = 0; i < 8; ++i)
#pragma unroll
                for (int j = 0; j < 8; ++j) acc[i][j] = fmaf(ar[i], br[j], acc[i][j]);
        }
    }
#pragma unroll
    for (int i = 0; i < 8; ++i) {
        int r = bm + (i >> 2) * 64 + ty * 4 + (i & 3);
#pragma unroll
        for (int jh = 0; jh < 2; ++jh) {
            int cb = bn + jh * 64 + tx * 4;
            float4 v = make_float4(acc[i][jh * 4 + 0], acc[i][jh * 4 + 1],
                                   acc[i][jh * 4 + 2], acc[i][jh * 4 + 3]);
            if (biasp) { v.x += biasp[cb]; v.y += biasp[cb + 1]; v.z += biasp[cb + 2]; v.w += biasp[cb + 3]; }
            if (ACT == 1) { v.x = gelu_f(v.x); v.y = gelu_f(v.y); v.z = gelu_f(v.z); v.w = gelu_f(v.w); }
            *reinterpret_cast<float4*>(C + (size_t)r * ldc + cb) = v;
        }
    }
}

// ---------------------------------------------------------------------------
// Scan: 64 WGs = 8 layers x 8 column-slices. Each WG holds its 128-col weight
// slice in REGISTERS (64 VGPR/lane) and computes all 8 batches per step via
// MFMA (M=8 rows = batches). Cross-WG exchange of raw GLU v + LN partials via
// agent-scope relaxed atomics (LLC-coherent) + monotone flags. No fences.
// ---------------------------------------------------------------------------
__global__ __launch_bounds__(512, 2) void k_scan5(
    const float* __restrict__ tokens,      // [B,T,L,D]
    const uint4* __restrict__ wswz,        // packed B-fragments
    const float* __restrict__ glu_b,       // [L,2D]
    const float* __restrict__ sc_sum, const float* __restrict__ ii_sum,
    const float* __restrict__ ln_glu_g, const float* __restrict__ ln_glu_b,
    const float* __restrict__ ln_state_g, const float* __restrict__ ln_state_b,
    float* __restrict__ vout,              // [B,T,L,D] raw v
    float* __restrict__ psum,              // [T,L,B,8,2]
    unsigned int* __restrict__ flags)      // [L,8] padded x16
{
    const int l = blockIdx.x & 7, q = blockIdx.x >> 3;
    const int tid = threadIdx.x, w = tid >> 6, lane = tid & 63;
    const int b = w;  // wave = batch in phases A/C

    __shared__ __align__(16) unsigned hn_pk[8][260];  // bf16 pairs, padded row
    __shared__ __align__(16) unsigned zbuf[4];
    __shared__ __align__(16) float red[8][128];

    // resident B-fragments: wave w = n-tile w (16 cols), 16 k-tiles
    uint4 wr[16];
    {
        const uint4* wp = wswz + ((((size_t)l * 8 + q) * 8 + w) * 16) * 64 + lane;
#pragma unroll
        for (int kt = 0; kt < 16; ++kt) wr[kt] = wp[kt * 64];
    }
    // per-dim params for dims d = lane*8 + j (phase A; same for every wave)
    const int d0 = lane * 8;
    float P_sc[8], P_ii[8], P_gg[8], P_gb[8], P_sg[8], P_sb[8];
#pragma unroll
    for (int j = 0; j < 8; j += 4) {
        *reinterpret_cast<float4*>(&P_sc[j]) = *reinterpret_cast<const float4*>(sc_sum + l * nD + d0 + j);
        *reinterpret_cast<float4*>(&P_ii[j]) = *reinterpret_cast<const float4*>(ii_sum + l * nD + d0 + j);
        *reinterpret_cast<float4*>(&P_gg[j]) = *reinterpret_cast<const float4*>(ln_glu_g + d0 + j);
        *reinterpret_cast<float4*>(&P_gb[j]) = *reinterpret_cast<const float4*>(ln_glu_b + d0 + j);
        *reinterpret_cast<float4*>(&P_sg[j]) = *reinterpret_cast<const float4*>(ln_state_g + d0 + j);
        *reinterpret_cast<float4*>(&P_sb[j]) = *reinterpret_cast<const float4*>(ln_state_b + d0 + j);
    }
    const float bA = glu_b[l * 1024 + q * 64 + lane];        // a-col bias
    const float bG = glu_b[l * 1024 + 512 + q * 64 + lane];  // g-col bias

    if (tid < 4) zbuf[tid] = 0u;

    const float* tokp = tokens + ((size_t)b * nT * nL + l) * nD + d0;
    float* vbase = vout + ((size_t)b * nT * nL + l) * nD;

    // A-fragment LDS source: row (lane&15) = batch, rows 8-15 -> zeros
    const unsigned* afp; int astep;
    {
        int bb = lane & 15, g = lane >> 4;
        if (bb < 8) { afp = &hn_pk[bb][g * 4]; astep = 16; }
        else        { afp = &zbuf[0];          astep = 0;  }
    }
    unsigned int* myflags = flags + l * 8 * 16;
    __syncthreads();

    for (int t = 0; t < nT; ++t) {
        // token prefetch (independent of sync)
        float4 tk0 = *reinterpret_cast<const float4*>(tokp + (size_t)t * nLD);
        float4 tk1 = *reinterpret_cast<const float4*>(tokp + (size_t)t * nLD + 4);

        float h[8];
        if (t > 0) {
            // wait for all 8 slices of step t-1 (monotone flags, relaxed)
            int ok;
            do {
                unsigned f = 0xffffffffu;
                if (tid < 8)
                    f = __hip_atomic_load(myflags + tid * 16,
                                          __ATOMIC_RELAXED, __HIP_MEMORY_SCOPE_AGENT);
                ok = (f >= (unsigned)t);
            } while (!__syncthreads_and(ok));

            // read v[t-1] + partials (agent-scope atomic loads -> LLC coherent)
            const float* vp = vbase + (size_t)(t - 1) * nLD + d0;
            float vv[8];
#pragma unroll
            for (int j = 0; j < 8; ++j)
                vv[j] = __hip_atomic_load(vp + j, __ATOMIC_RELAXED,
                                          __HIP_MEMORY_SCOPE_AGENT);
            float ppx = 0.f, ppy = 0.f;
            if (lane < 8) {
                const float* pq = psum + ((((size_t)(t - 1) * nL + l) * nB + b) * 8 + lane) * 2;
                ppx = __hip_atomic_load(pq,     __ATOMIC_RELAXED, __HIP_MEMORY_SCOPE_AGENT);
                ppy = __hip_atomic_load(pq + 1, __ATOMIC_RELAXED, __HIP_MEMORY_SCOPE_AGENT);
            }
            float S = ppx, Q = ppy;
#pragma unroll
            for (int o = 32; o > 0; o >>= 1) { S += __shfl_xor(S, o, 64); Q += __shfl_xor(Q, o, 64); }
            const float mv = S * (1.f / nD);
            const float iv = rsqrtf(Q * (1.f / nD) - mv * mv + 1e-5f);
            float tk[8] = {tk0.x, tk0.y, tk0.z, tk0.w, tk1.x, tk1.y, tk1.z, tk1.w};
#pragma unroll
            for (int j = 0; j < 8; ++j) {
                float st = (vv[j] - mv) * iv * P_sg[j] + P_sb[j];
                h[j] = st * P_sc[j] + tk[j] * P_ii[j];
            }
        } else {
            float tk[8] = {tk0.x, tk0.y, tk0.z, tk0.w, tk1.x, tk1.y, tk1.z, tk1.w};
#pragma unroll
            for (int j = 0; j < 8; ++j) h[j] = tk[j] * P_ii[j];
        }

        // LN over the wave's full 512 dims (wave = batch)
        float S = 0.f, Q = 0.f;
#pragma unroll
        for (int j = 0; j < 8; ++j) { S += h[j]; Q += h[j] * h[j]; }
#pragma unroll
        for (int o = 32; o > 0; o >>= 1) { S += __shfl_xor(S, o, 64); Q += __shfl_xor(Q, o, 64); }
        const float mh = S * (1.f / nD);
        const float ih = rsqrtf(Q * (1.f / nD) - mh * mh + 1e-5f);
        unsigned pr[4];
#pragma unroll
        for (int p = 0; p < 4; ++p) {
            float a0 = (h[2 * p]     - mh) * ih * P_gg[2 * p]     + P_gb[2 * p];
            float a1 = (h[2 * p + 1] - mh) * ih * P_gg[2 * p + 1] + P_gb[2 * p + 1];
            pr[p] = (unsigned)f2bf(a0) | ((unsigned)f2bf(a1) << 16);
        }
        *reinterpret_cast<uint4*>(&hn_pk[b][lane * 4]) = make_uint4(pr[0], pr[1], pr[2], pr[3]);
        __syncthreads();  // BAR1: hn ready

        // MFMA: acc rows = batches (0-7), cols = n-tile w's 16 cols
        f32x4 acc = {0.f, 0.f, 0.f, 0.f};
#pragma unroll
        for (int kt = 0; kt < 16; ++kt) {
            short8v af = *reinterpret_cast<const short8v*>(afp + kt * astep);
            short8v bf = __builtin_bit_cast(short8v, wr[kt]);
            acc = __builtin_amdgcn_mfma_f32_16x16x32_bf16(af, bf, acc, 0, 0, 0);
        }
        if (lane < 32) {
            const int r0 = (lane >> 4) * 4, col = lane & 15;
            red[r0 + 0][w * 16 + col] = acc.x;
            red[r0 + 1][w * 16 + col] = acc.y;
            red[r0 + 2][w * 16 + col] = acc.z;
            red[r0 + 3][w * 16 + col] = acc.w;
        }
        __syncthreads();  // BAR2: red ready

        // phase C: wave = batch b, lane = column within q-slice
        {
            float a = red[b][lane]      + bA;
            float g = red[b][64 + lane] + bG;
            float v = a / (1.f + __expf(-g));
            float s2 = v, q2 = v * v;
#pragma unroll
            for (int o = 32; o > 0; o >>= 1) { s2 += __shfl_xor(s2, o, 64); q2 += __shfl_xor(q2, o, 64); }
            __hip_atomic_store(vbase + (size_t)t * nLD + q * 64 + lane, v,
                               __ATOMIC_RELAXED, __HIP_MEMORY_SCOPE_AGENT);
            if (lane == 0) {
                float* pq = psum + ((((size_t)t * nL + l) * nB + b) * 8 + q) * 2;
                __hip_atomic_store(pq,     s2, __ATOMIC_RELAXED, __HIP_MEMORY_SCOPE_AGENT);
                __hip_atomic_store(pq + 1, q2, __ATOMIC_RELAXED, __HIP_MEMORY_SCOPE_AGENT);
            }
        }
        asm volatile("s_waitcnt vmcnt(0)" ::: "memory");  // every wave drains its stores
        __syncthreads();  // BAR3: all stores visible at LLC
        if (tid == 0)
            __hip_atomic_store(myflags + q * 16, (unsigned)(t + 1),
                               __ATOMIC_RELAXED, __HIP_MEMORY_SCOPE_AGENT);
    }
}

// y = LN_ff( LN_state(raw v) * os_sum[l] ); one wave per (b,t,l) row
__global__ __launch_bounds__(256) void k_y2(
    const float* __restrict__ vout, const float* __restrict__ psum,
    const float* __restrict__ os_sum,
    const float* __restrict__ lsg, const float* __restrict__ lsb,
    const float* __restrict__ fg, const float* __restrict__ fb,
    float* __restrict__ y)
{
    const int row = blockIdx.x * 4 + (threadIdx.x >> 6);   // over B*T*L
    const int lane = threadIdx.x & 63;
    const int l = row & 7;
    const int bt = row >> 3;
    const int t = bt & (nT - 1);
    const int b = bt >> 9;

    float S = 0.f, Q = 0.f;
    if (lane < 8) {
        const float* pq = psum + ((((size_t)t * nL + l) * nB + b) * 8 + lane) * 2;
        S = pq[0]; Q = pq[1];
    }
#pragma unroll
    for (int o = 32; o > 0; o >>= 1) { S += __shfl_xor(S, o, 64); Q += __shfl_xor(Q, o, 64); }
    const float mv = S * (1.f / nD);
    const float iv = rsqrtf(Q * (1.f / nD) - mv * mv + 1e-5f);

    const float* vp = vout + (size_t)row * nD;
    const float* op = os_sum + l * nD;
    const int base = lane * 8;
    float val[8];
    float s2 = 0.f, q2 = 0.f;
#pragma unroll
    for (int j = 0; j < 8; j += 4) {
        float4 v4 = *reinterpret_cast<const float4*>(vp + base + j);
        float4 o4 = *reinterpret_cast<const float4*>(op + base + j);
        float4 g4 = *reinterpret_cast<const float4*>(lsg + base + j);
        float4 b4 = *reinterpret_cast<const float4*>(lsb + base + j);
        val[j]     = ((v4.x - mv) * iv * g4.x + b4.x) * o4.x;
        val[j + 1] = ((v4.y - mv) * iv * g4.y + b4.y) * o4.y;
        val[j + 2] = ((v4.z - mv) * iv * g4.z + b4.z) * o4.z;
        val[j + 3] = ((v4.w - mv) * iv * g4.w + b4.w) * o4.w;
    }
#pragma unroll
    for (int j = 0; j < 8; ++j) { s2 += val[j]; q2 += val[j] * val[j]; }
#pragma unroll
    for (int o = 32; o > 0; o >>= 1) { s2 += __shfl_xor(s2, o, 64); q2 += __shfl_xor(q2, o, 64); }
    const float m2 = s2 * (1.f / nD);
    const float i2 = rsqrtf(q2 * (1.f / nD) - m2 * m2 + 1e-5f);
    const float* gp = fg + l * nD;
    const float* bp = fb + l * nD;
    float* yp = y + (size_t)row * nD;
#pragma unroll
    for (int j = 0; j < 8; j += 4) {
        float4 g4 = *reinterpret_cast<const float4*>(gp + base + j);
        float4 b4 = *reinterpret_cast<const float4*>(bp + base + j);
        float4 o;
        o.x = (val[j]     - m2) * i2 * g4.x + b4.x;
        o.y = (val[j + 1] - m2) * i2 * g4.y + b4.y;
        o.z = (val[j + 2] - m2) * i2 * g4.z + b4.z;
        o.w = (val[j + 3] - m2) * i2 * g4.w + b4.w;
        *reinterpret_cast<float4*>(yp + base + j) = o;
    }
}

// scores from h via w2a; softmax over L; scale h in place; store probs
__global__ __launch_bounds__(256) void k_scores(
    float* __restrict__ h, const float* __restrict__ w2a,
    const float* __restrict__ c2, const float* __restrict__ attn_b,
    float* __restrict__ scores)
{
    const int bt = blockIdx.x;
    const int tid = threadIdx.x, wid = tid >> 6, lane = tid & 63;
    __shared__ float slog[nL];
    float* hrow = h + (size_t)bt * nLD;
    for (int l = wid; l < nL; l += 4) {
        const float* hp = hrow + l * nD;
        const float* wp = w2a + l * nD;
        float s = 0.f;
        for (int i = lane; i < nD; i += 64) s += hp[i] * wp[i];
#pragma unroll
        for (int off = 32; off > 0; off >>= 1) s += __shfl_down(s, off, 64);
        if (lane == 0) slog[l] = s + c2[l] + attn_b[0];
    }
    __syncthreads();
    float mx = -1e30f;
#pragma unroll
    for (int l = 0; l < nL; ++l) mx = fmaxf(mx, slog[l]);
    float den = 0.f;
#pragma unroll
    for (int l = 0; l < nL; ++l) den += __expf(slog[l] - mx);
    float rden = 1.f / den;
#pragma unroll
    for (int it = 0; it < 4; ++it) {
        int idx = tid * 4 + it * 1024;
        int l = idx >> 9;
        float s = __expf(slog[l] - mx) * rden;
        float4 v = *reinterpret_cast<float4*>(hrow + idx);
        v.x *= s; v.y *= s; v.z *= s; v.w *= s;
        *reinterpret_cast<float4*>(hrow + idx) = v;
    }
    if (tid < nL) scores[bt * nL + tid] = __expf(slog[tid] - mx) * rden;
}

// out = LN( wbuf + sum_l s_l * ff_b2[l] ) with ln_emb params
__global__ __launch_bounds__(256) void k_final(
    const float* __restrict__ wbuf, const float* __restrict__ scores,
    const float* __restrict__ ff_b2, const float* __restrict__ g,
    const float* __restrict__ bvec, float* __restrict__ out)
{
    const int bt = blockIdx.x;
    const int tid = threadIdx.x;
    __shared__ float ssc[nL];
    __shared__ float red[8];
    if (tid < nL) ssc[tid] = scores[bt * nL + tid];
    __syncthreads();
    const int e0 = tid * 4;
    float4 w = *reinterpret_cast<const float4*>(wbuf + (size_t)bt * nE + e0);
#pragma unroll
    for (int l = 0; l < nL; ++l) {
        float s = ssc[l];
        float4 b2 = *reinterpret_cast<const float4*>(ff_b2 + l * nE + e0);
        w.x += s * b2.x; w.y += s * b2.y; w.z += s * b2.z; w.w += s * b2.w;
    }
    float sum = w.x + w.y + w.z + w.w;
    float sq = w.x * w.x + w.y * w.y + w.z * w.z + w.w * w.w;
    int wid = tid >> 6, lane = tid & 63;
#pragma unroll
    for (int off = 32; off > 0; off >>= 1) {
        sum += __shfl_down(sum, off, 64); sq += __shfl_down(sq, off, 64);
    }
    if (lane == 0) { red[wid] = sum; red[4 + wid] = sq; }
    __syncthreads();
    sum = red[0] + red[1] + red[2] + red[3];
    sq  = red[4] + red[5] + red[6] + red[7];
    float mean = sum * (1.f / nE);
    float inv = rsqrtf(sq * (1.f / nE) - mean * mean + 1e-5f);
    float4 g4 = *reinterpret_cast<const float4*>(g + e0);
    float4 b4 = *reinterpret_cast<const float4*>(bvec + e0);
    float4 o;
    o.x = (w.x - mean) * inv * g4.x + b4.x;
    o.y = (w.y - mean) * inv * g4.y + b4.y;
    o.z = (w.z - mean) * inv * g4.z + b4.z;
    o.w = (w.w - mean) * inv * g4.w + b4.w;
    *reinterpret_cast<float4*>(out + (size_t)bt * nE + e0) = o;
}

extern "C" void kernel_launch(void* const* d_in, const int* in_sizes, int n_in,
                              void* d_out, int out_size, void* d_ws, size_t ws_size,
                              hipStream_t stream) {
    (void)in_sizes; (void)n_in; (void)out_size; (void)ws_size;
    const float* emb            = (const float*)d_in[0];
    const float* state_control  = (const float*)d_in[1];
    const float* input_influence= (const float*)d_in[2];
    const float* output_shaper  = (const float*)d_in[3];
    const float* glu_w          = (const float*)d_in[4];
    const float* glu_b          = (const float*)d_in[5];
    const float* e2s_w          = (const float*)d_in[6];
    const float* e2s_b          = (const float*)d_in[7];
    const float* ln_glu_g       = (const float*)d_in[8];
    const float* ln_glu_b       = (const float*)d_in[9];
    const float* ln_state_g     = (const float*)d_in[10];
    const float* ln_state_b     = (const float*)d_in[11];
    const float* ln_emb_g       = (const float*)d_in[12];
    const float* ln_emb_b       = (const float*)d_in[13];
    const float* ff_ln_g        = (const float*)d_in[14];
    const float* ff_ln_b        = (const float*)d_in[15];
    const float* ff_w1          = (const float*)d_in[16];
    const float* ff_b1          = (const float*)d_in[17];
    const float* ff_w2          = (const float*)d_in[18];
    const float* ff_b2          = (const float*)d_in[19];
    const float* attn_w         = (const float*)d_in[20];
    const float* attn_b         = (const float*)d_in[21];

    // workspace layout (~145 MB)
    char* ws = (char*)d_ws;
    float* tokens = (float*)ws;  ws += (size_t)nBT * nLD * 4;             // 67 MB (later: y, then wbuf)
    float* vbuf   = (float*)ws;  ws += (size_t)nBT * nLD * 4;             // 67 MB raw v (later: h)
    uint4* wswz   = (uint4*)ws;  ws += (size_t)nL * 8 * 8 * 16 * 64 * 16; // 8 MB packed B-frags
    float* psum   = (float*)ws;  ws += (size_t)nT * nL * nB * 8 * 2 * 4;  // 2 MB
    float* sc_sum = (float*)ws;  ws += nLD * 4;
    float* ii_sum = (float*)ws;  ws += nLD * 4;
    float* os_sum = (float*)ws;  ws += nLD * 4;
    float* w2a    = (float*)ws;  ws += nLD * 4;
    float* c2     = (float*)ws;  ws += 256;
    float* scores = (float*)ws;  ws += (size_t)nBT * nL * 4;
    unsigned int* flags = (unsigned int*)ws; ws += nL * 8 * 16 * 4;
    float* wbuf = tokens;  // alias: tokens (y) dead after ff1 GEMM

    // precompute
    k_init<<<4, 256, 0, stream>>>(flags);
    k_pack2<<<nL * 64, 256, 0, stream>>>(glu_w, wswz);
    k_wdot<<<1024, 256, 0, stream>>>(state_control, nullptr, sc_sum, nLD, nD);
    k_wdot<<<1024, 256, 0, stream>>>(input_influence, nullptr, ii_sum, nLD, nD);
    k_wdot<<<1024, 256, 0, stream>>>(output_shaper, nullptr, os_sum, nLD, nD);
    k_wdot<<<1024, 256, 0, stream>>>(ff_w2, attn_w, w2a, nLD, nE);
    k_wdot<<<2, 256, 0, stream>>>(ff_b2, attn_w, c2, nL, nE);

    // tokens = emb @ e2s_w + e2s_b   [4096 x 4096], K=1024
    k_gemm<0><<<dim3(32, 32, 1), 256, 0, stream>>>(
        emb, nE, 0, e2s_w, nLD, 0, e2s_b, 0, tokens, nLD, 0, nBT, nLD, nE);

    // distributed recurrent scan -> raw v + partials
    k_scan5<<<64, 512, 0, stream>>>(tokens, wswz, glu_b, sc_sum, ii_sum,
                                    ln_glu_g, ln_glu_b, ln_state_g, ln_state_b,
                                    vbuf, psum, flags);

    // y = LN_ff(LN_state(v) * os_sum)  (into tokens buffer)
    k_y2<<<nBT * nL / 4, 256, 0, stream>>>(vbuf, psum, os_sum,
                                           ln_state_g, ln_state_b,
                                           ff_ln_g, ff_ln_b, tokens);

    // h = GELU(y @ ff_w1 + ff_b1), per-layer batched  (into vbuf)
    k_gemm<1><<<dim3(4, 32, 8), 256, 0, stream>>>(
        tokens, nLD, nD, ff_w1, nD, (long long)nD * nD, ff_b1, nD,
        vbuf, nLD, nD, nBT, nD, nD);

    // scores + scale h in place
    k_scores<<<nBT, 256, 0, stream>>>(vbuf, w2a, c2, attn_b, scores);

    // weighted = (s*h) @ W2cat   [4096 x 1024], K=4096  (into wbuf=tokens)
    k_gemm<0><<<dim3(8, 32, 1), 256, 0, stream>>>(
        vbuf, nLD, 0, ff_w2, nE, 0, nullptr, 0, wbuf, nE, 0, nBT, nE, nLD);

    // out = LN(weighted + sum_l s_l*ff_b2[l])
    k_final<<<nBT, 256, 0, stream>>>(wbuf, scores, ff_b2, ln_emb_g, ln_emb_b, (float*)d_out);
}

// Round 6
// 3631.371 us; speedup vs baseline: 4.5849x; 1.1122x over previous
//
#include <hip/hip_runtime.h>
#include <hip/hip_bf16.h>
#include <math.h>

// Fixed problem dims
static constexpr int nB = 8, nT = 512, nE = 1024, nL = 8, nD = 512;
static constexpr int nBT = nB * nT;   // 4096 rows (b,t)
static constexpr int nLD = nL * nD;   // 4096

typedef __attribute__((ext_vector_type(8))) short short8v;  // 8 bf16 (4 VGPRs)
typedef __attribute__((ext_vector_type(4))) float f32x4;

__device__ __forceinline__ unsigned short f2bf(float f) {
    unsigned int u = __float_as_uint(f);
    return (unsigned short)((u + 0x7fffu + ((u >> 16) & 1u)) >> 16);  // RNE
}
__device__ __forceinline__ float gelu_f(float x) {
    return 0.5f * x * (1.0f + erff(x * 0.70710678118654752f));  // exact GELU
}

// dst[r] = sum_i src[r,i] * (w ? w[i] : 1)
__global__ __launch_bounds__(256) void k_wdot(const float* __restrict__ src,
                                              const float* __restrict__ w,
                                              float* __restrict__ dst,
                                              int rows, int rowlen) {
    int row = blockIdx.x * 4 + (threadIdx.x >> 6);
    if (row >= rows) return;
    int lane = threadIdx.x & 63;
    const float* p = src + (size_t)row * rowlen;
    float s = 0.f;
    if (w) { for (int i = lane; i < rowlen; i += 64) s += p[i] * w[i]; }
    else   { for (int i = lane; i < rowlen; i += 64) s += p[i]; }
#pragma unroll
    for (int off = 32; off > 0; off >>= 1) s += __shfl_down(s, off, 64);
    if (lane == 0) dst[row] = s;
}

__global__ void k_init(unsigned int* f) {
    if (threadIdx.x < nL * 8) f[threadIdx.x] = 0u;
}

// Pack glu_w into MFMA B-fragment layout with INTERLEAVED a/g columns:
// frag col j: j=2u -> a-col q*64+w*8+u ; j=2u+1 -> g-col 512+q*64+w*8+u.
// dst[((l*8+q)*8+w)*16+kt][lane]: pairs p -> k = 32kt+8*(lane>>4)+2p(+1).
__global__ __launch_bounds__(256) void k_pack2(const float* __restrict__ src,
                                               uint4* __restrict__ dst) {
    const int blk = blockIdx.x;            // l*64 + q*8 + w   (512 blocks)
    const int w = blk & 7, q = (blk >> 3) & 7, l = blk >> 6;
    const float* wl = src + (size_t)l * nD * 1024;
    for (int i = threadIdx.x; i < 16 * 64; i += 256) {
        const int kt = i >> 6, ln = i & 63;
        const int j = ln & 15, g = ln >> 4;
        const int u = j >> 1;
        const int col = (j & 1) ? (512 + q * 64 + w * 8 + u)
                                : (q * 64 + w * 8 + u);
        const int k0 = 32 * kt + 8 * g;
        unsigned pr[4];
#pragma unroll
        for (int p = 0; p < 4; ++p) {
            float a = wl[(size_t)(k0 + 2 * p) * 1024 + col];
            float c = wl[(size_t)(k0 + 2 * p + 1) * 1024 + col];
            pr[p] = (unsigned)f2bf(a) | ((unsigned)f2bf(c) << 16);
        }
        dst[((((size_t)l * 8 + q) * 8 + w) * 16 + kt) * 64 + ln] =
            make_uint4(pr[0], pr[1], pr[2], pr[3]);
    }
}

// C[m,n] = act( sum_k A[m,k]*B[k,n] + bias[n] ), 128x128 tile, BK=16, fp32
template<int ACT>
__global__ __launch_bounds__(256) void k_gemm(
    const float* __restrict__ A, int lda, long long sA,
    const float* __restrict__ Bm, int ldb, long long sB,
    const float* __restrict__ bias, long long sBias,
    float* __restrict__ C, int ldc, long long sC,
    int M, int N, int K)
{
    A  += (size_t)blockIdx.z * sA;
    Bm += (size_t)blockIdx.z * sB;
    C  += (size_t)blockIdx.z * sC;
    const float* biasp = bias ? bias + (size_t)blockIdx.z * sBias : nullptr;

    __shared__ __align__(16) float As[16][128];
    __shared__ __align__(16) float Bs[16][128];
    const int tid = threadIdx.x;
    const int tx = tid & 15, ty = tid >> 4;
    const int bm = blockIdx.y * 128, bn = blockIdx.x * 128;

    float acc[8][8];
#pragma unroll
    for (int i = 0; i < 8; ++i)
#pragma unroll
        for (int j = 0; j < 8; ++j) acc[i][j] = 0.f;

    const int arow = tid >> 1, ac8 = (tid & 1) * 8;
    const int brow = tid >> 4, bc8 = (tid & 15) * 8;

    for (int kt = 0; kt < K; kt += 16) {
        float4 a0 = *reinterpret_cast<const float4*>(A + (size_t)(bm + arow) * lda + kt + ac8);
        float4 a1 = *reinterpret_cast<const float4*>(A + (size_t)(bm + arow) * lda + kt + ac8 + 4);
        float4 b0 = *reinterpret_cast<const float4*>(Bm + (size_t)(kt + brow) * ldb + bn + bc8);
        float4 b1 = *reinterpret_cast<const float4*>(Bm + (size_t)(kt + brow) * ldb + bn + bc8 + 4);
        __syncthreads();
        As[ac8 + 0][arow] = a0.x; As[ac8 + 1][arow] = a0.y;
        As[ac8 + 2][arow] = a0.z; As[ac8 + 3][arow] = a0.w;
        As[ac8 + 4][arow] = a1.x; As[ac8 + 5][arow] = a1.y;
        As[ac8 + 6][arow] = a1.z; As[ac8 + 7][arow] = a1.w;
        *reinterpret_cast<float4*>(&Bs[brow][bc8]) = b0;
        *reinterpret_cast<float4*>(&Bs[brow][bc8 + 4]) = b1;
        __syncthreads();
#pragma unroll
        for (int kk = 0; kk < 16; ++kk) {
            float ar[8], br[8];
            *reinterpret_cast<float4*>(&ar[0]) = *reinterpret_cast<const float4*>(&As[kk][ty * 4]);
            *reinterpret_cast<float4*>(&ar[4]) = *reinterpret_cast<const float4*>(&As[kk][64 + ty * 4]);
            *reinterpret_cast<float4*>(&br[0]) = *reinterpret_cast<const float4*>(&Bs[kk][tx * 4]);
            *reinterpret_cast<float4*>(&br[4]) = *reinterpret_cast<const float4*>(&Bs[kk][64 + tx * 4]);
#pragma unroll
            for (int i = 0; i < 8; ++i)
#pragma unroll
                for (int j = 0; j < 8; ++j) acc[i][j] = fmaf(ar[i], br[j], acc[i][j]);
        }
    }
#pragma unroll
    for (int i = 0; i < 8; ++i) {
        int r = bm + (i >> 2) * 64 + ty * 4 + (i & 3);
#pragma unroll
        for (int jh = 0; jh < 2; ++jh) {
            int cb = bn + jh * 64 + tx * 4;
            float4 v = make_float4(acc[i][jh * 4 + 0], acc[i][jh * 4 + 1],
                                   acc[i][jh * 4 + 2], acc[i][jh * 4 + 3]);
            if (biasp) { v.x += biasp[cb]; v.y += biasp[cb + 1]; v.z += biasp[cb + 2]; v.w += biasp[cb + 3]; }
            if (ACT == 1) { v.x = gelu_f(v.x); v.y = gelu_f(v.y); v.z = gelu_f(v.z); v.w = gelu_f(v.w); }
            *reinterpret_cast<float4*>(C + (size_t)r * ldc + cb) = v;
        }
    }
}

// ---------------------------------------------------------------------------
// Scan: 64 WGs = 8 layers x 8 column-slices; weights register-resident; MFMA
// with interleaved a/g frag cols -> GLU via shfl_xor(1) in-register, v stored
// straight from acc. Deferred LN: consumers recompute stats from the v row.
// Wave-level flag poll (no barrier); 2 raw barriers/step with minimal waits.
// ---------------------------------------------------------------------------
__global__ __launch_bounds__(512, 2) void k_scan6(
    const float* __restrict__ tokens,      // [B,T,L,D]
    const uint4* __restrict__ wswz,        // packed B-fragments (interleaved)
    const float* __restrict__ glu_b,       // [L,2D]
    const float* __restrict__ sc_sum, const float* __restrict__ ii_sum,
    const float* __restrict__ ln_glu_g, const float* __restrict__ ln_glu_b,
    const float* __restrict__ ln_state_g, const float* __restrict__ ln_state_b,
    float* __restrict__ vout,              // [B,T,L,D] raw v
    unsigned int* __restrict__ flags)      // [L,8]
{
    const int l = blockIdx.x & 7, q = blockIdx.x >> 3;
    const int tid = threadIdx.x, w = tid >> 6, lane = tid & 63;
    const int b = w;  // wave = batch in phase A

    __shared__ __align__(16) unsigned hn_pk[8][260];  // bf16 pairs, padded row
    __shared__ __align__(16) unsigned zbuf[4];

    // resident B-fragments: wave w = n-tile w, 16 k-tiles
    uint4 wr[16];
    {
        const uint4* wp = wswz + ((((size_t)l * 8 + q) * 8 + w) * 16) * 64 + lane;
#pragma unroll
        for (int kt = 0; kt < 16; ++kt) wr[kt] = wp[kt * 64];
    }
    // per-dim params for dims d = lane*8 + j
    const int d0 = lane * 8;
    float P_sc[8], P_ii[8], P_gg[8], P_gb[8], P_sg[8], P_sb[8];
#pragma unroll
    for (int j = 0; j < 8; j += 4) {
        *reinterpret_cast<float4*>(&P_sc[j]) = *reinterpret_cast<const float4*>(sc_sum + l * nD + d0 + j);
        *reinterpret_cast<float4*>(&P_ii[j]) = *reinterpret_cast<const float4*>(ii_sum + l * nD + d0 + j);
        *reinterpret_cast<float4*>(&P_gg[j]) = *reinterpret_cast<const float4*>(ln_glu_g + d0 + j);
        *reinterpret_cast<float4*>(&P_gb[j]) = *reinterpret_cast<const float4*>(ln_glu_b + d0 + j);
        *reinterpret_cast<float4*>(&P_sg[j]) = *reinterpret_cast<const float4*>(ln_state_g + d0 + j);
        *reinterpret_cast<float4*>(&P_sb[j]) = *reinterpret_cast<const float4*>(ln_state_b + d0 + j);
    }
    // phase-C per-lane column (interleaved frag cols) and bias
    const int cu = (lane & 15) >> 1;
    const int mycol = (lane & 1) ? (512 + q * 64 + w * 8 + cu)
                                 : (q * 64 + w * 8 + cu);
    const float bias_c = glu_b[l * 1024 + mycol];
    const int vcol = q * 64 + w * 8 + cu;   // state dim written by even lanes

    if (tid < 4) zbuf[tid] = 0u;

    const float* tokp = tokens + ((size_t)b * nT * nL + l) * nD + d0;
    const float* vbase = vout + ((size_t)b * nT * nL + l) * nD;  // consumer view

    // A-fragment LDS source: frag row (lane&15) = batch, rows 8-15 -> zeros
    const unsigned* afp; int astep;
    {
        int bb = lane & 15, g = lane >> 4;
        if (bb < 8) { afp = &hn_pk[bb][g * 4]; astep = 16; }
        else        { afp = &zbuf[0];          astep = 0;  }
    }
    unsigned int* lf = flags + l * 8;
    __syncthreads();

    // preload token t=0
    float4 tk0 = *reinterpret_cast<const float4*>(tokp);
    float4 tk1 = *reinterpret_cast<const float4*>(tokp + 4);

    for (int t = 0; t < nT; ++t) {
        float tk[8] = {tk0.x, tk0.y, tk0.z, tk0.w, tk1.x, tk1.y, tk1.z, tk1.w};
        float h[8];
        if (t > 0) {
            // wave-level poll: 8 flags on one 32B line, no cross-wave barrier
            int ok;
            do {
                unsigned f = 0xffffffffu;
                if (lane < 8)
                    f = __hip_atomic_load(lf + lane, __ATOMIC_RELAXED,
                                          __HIP_MEMORY_SCOPE_AGENT);
                ok = (f >= (unsigned)t);
            } while (!__all(ok));

            // load v[t-1] row for batch b; compute LN stats locally
            const float* vp = vbase + (size_t)(t - 1) * nLD + d0;
            float vv[8];
#pragma unroll
            for (int j = 0; j < 8; ++j)
                vv[j] = __hip_atomic_load(vp + j, __ATOMIC_RELAXED,
                                          __HIP_MEMORY_SCOPE_AGENT);
            float S = 0.f, Q = 0.f;
#pragma unroll
            for (int j = 0; j < 8; ++j) { S += vv[j]; Q += vv[j] * vv[j]; }
#pragma unroll
            for (int o = 32; o > 0; o >>= 1) { S += __shfl_xor(S, o, 64); Q += __shfl_xor(Q, o, 64); }
            const float mv = S * (1.f / nD);
            const float iv = rsqrtf(Q * (1.f / nD) - mv * mv + 1e-5f);
#pragma unroll
            for (int j = 0; j < 8; ++j) {
                float st = (vv[j] - mv) * iv * P_sg[j] + P_sb[j];
                h[j] = st * P_sc[j] + tk[j] * P_ii[j];
            }
        } else {
#pragma unroll
            for (int j = 0; j < 8; ++j) h[j] = tk[j] * P_ii[j];
        }

        // issue token prefetch for t+1 (stays in flight across raw BAR1)
        if (t + 1 < nT) {
            tk0 = *reinterpret_cast<const float4*>(tokp + (size_t)(t + 1) * nLD);
            tk1 = *reinterpret_cast<const float4*>(tokp + (size_t)(t + 1) * nLD + 4);
        }

        // LN(h) over the wave's 512 dims (wave = batch)
        float S = 0.f, Q = 0.f;
#pragma unroll
        for (int j = 0; j < 8; ++j) { S += h[j]; Q += h[j] * h[j]; }
#pragma unroll
        for (int o = 32; o > 0; o >>= 1) { S += __shfl_xor(S, o, 64); Q += __shfl_xor(Q, o, 64); }
        const float mh = S * (1.f / nD);
        const float ih = rsqrtf(Q * (1.f / nD) - mh * mh + 1e-5f);
        unsigned pr[4];
#pragma unroll
        for (int p = 0; p < 4; ++p) {
            float a0 = (h[2 * p]     - mh) * ih * P_gg[2 * p]     + P_gb[2 * p];
            float a1 = (h[2 * p + 1] - mh) * ih * P_gg[2 * p + 1] + P_gb[2 * p + 1];
            pr[p] = (unsigned)f2bf(a0) | ((unsigned)f2bf(a1) << 16);
        }
        *reinterpret_cast<uint4*>(&hn_pk[b][lane * 4]) = make_uint4(pr[0], pr[1], pr[2], pr[3]);

        // BAR1: hn ready (LDS only -> lgkmcnt; token prefetch stays in flight)
        asm volatile("s_waitcnt lgkmcnt(0)" ::: "memory");
        __builtin_amdgcn_s_barrier();
        __builtin_amdgcn_sched_barrier(0);

        // MFMA: rows = batches, cols = wave's interleaved 16-col tile
        f32x4 acc0 = {0.f, 0.f, 0.f, 0.f}, acc1 = {0.f, 0.f, 0.f, 0.f};
#pragma unroll
        for (int kt = 0; kt < 8; ++kt) {
            short8v a0 = *reinterpret_cast<const short8v*>(afp + (2 * kt) * astep);
            short8v a1 = *reinterpret_cast<const short8v*>(afp + (2 * kt + 1) * astep);
            acc0 = __builtin_amdgcn_mfma_f32_16x16x32_bf16(
                a0, __builtin_bit_cast(short8v, wr[2 * kt]), acc0, 0, 0, 0);
            acc1 = __builtin_amdgcn_mfma_f32_16x16x32_bf16(
                a1, __builtin_bit_cast(short8v, wr[2 * kt + 1]), acc1, 0, 0, 0);
        }

        // GLU in-register: even frag col holds a, odd holds g; pair via xor(1)
        float x[4], y[4];
#pragma unroll
        for (int i = 0; i < 4; ++i) x[i] = acc0[i] + acc1[i] + bias_c;
#pragma unroll
        for (int i = 0; i < 4; ++i) y[i] = __shfl_xor(x[i], 1, 64);
        if ((lane < 32) && !(lane & 1)) {
            const int r0 = (lane >> 4) * 4;
#pragma unroll
            for (int i = 0; i < 4; ++i) {
                float v = x[i] / (1.f + __expf(-y[i]));
                __hip_atomic_store(
                    vout + (((size_t)(r0 + i) * nT + t) * nL + l) * nD + vcol,
                    v, __ATOMIC_RELAXED, __HIP_MEMORY_SCOPE_AGENT);
            }
        }

        // BAR3: all waves' v-stores drained, then publish monotone flag
        asm volatile("s_waitcnt vmcnt(0)" ::: "memory");
        __builtin_amdgcn_s_barrier();
        if (tid == 0 && t + 1 < nT)
            __hip_atomic_store(lf + q, (unsigned)(t + 1),
                               __ATOMIC_RELAXED, __HIP_MEMORY_SCOPE_AGENT);
    }
}

// y = LN_ff( LN_state(raw v) * os_sum[l] ); stats computed from the row
__global__ __launch_bounds__(256) void k_y2(
    const float* __restrict__ vout, const float* __restrict__ os_sum,
    const float* __restrict__ lsg, const float* __restrict__ lsb,
    const float* __restrict__ fg, const float* __restrict__ fb,
    float* __restrict__ y)
{
    const int row = blockIdx.x * 4 + (threadIdx.x >> 6);   // over B*T*L
    const int lane = threadIdx.x & 63;
    const int l = row & 7;

    const float* vp = vout + (size_t)row * nD;
    const int base = lane * 8;
    float vv[8];
    *reinterpret_cast<float4*>(&vv[0]) = *reinterpret_cast<const float4*>(vp + base);
    *reinterpret_cast<float4*>(&vv[4]) = *reinterpret_cast<const float4*>(vp + base + 4);
    float S = 0.f, Q = 0.f;
#pragma unroll
    for (int j = 0; j < 8; ++j) { S += vv[j]; Q += vv[j] * vv[j]; }
#pragma unroll
    for (int o = 32; o > 0; o >>= 1) { S += __shfl_xor(S, o, 64); Q += __shfl_xor(Q, o, 64); }
    const float mv = S * (1.f / nD);
    const float iv = rsqrtf(Q * (1.f / nD) - mv * mv + 1e-5f);

    const float* op = os_sum + l * nD;
    float val[8];
    float s2 = 0.f, q2 = 0.f;
#pragma unroll
    for (int j = 0; j < 8; j += 4) {
        float4 o4 = *reinterpret_cast<const float4*>(op + base + j);
        float4 g4 = *reinterpret_cast<const float4*>(lsg + base + j);
        float4 b4 = *reinterpret_cast<const float4*>(lsb + base + j);
        val[j]     = ((vv[j]     - mv) * iv * g4.x + b4.x) * o4.x;
        val[j + 1] = ((vv[j + 1] - mv) * iv * g4.y + b4.y) * o4.y;
        val[j + 2] = ((vv[j + 2] - mv) * iv * g4.z + b4.z) * o4.z;
        val[j + 3] = ((vv[j + 3] - mv) * iv * g4.w + b4.w) * o4.w;
    }
#pragma unroll
    for (int j = 0; j < 8; ++j) { s2 += val[j]; q2 += val[j] * val[j]; }
#pragma unroll
    for (int o = 32; o > 0; o >>= 1) { s2 += __shfl_xor(s2, o, 64); q2 += __shfl_xor(q2, o, 64); }
    const float m2 = s2 * (1.f / nD);
    const float i2 = rsqrtf(q2 * (1.f / nD) - m2 * m2 + 1e-5f);
    const float* gp = fg + l * nD;
    const float* bp = fb + l * nD;
    float* yp = y + (size_t)row * nD;
#pragma unroll
    for (int j = 0; j < 8; j += 4) {
        float4 g4 = *reinterpret_cast<const float4*>(gp + base + j);
        float4 b4 = *reinterpret_cast<const float4*>(bp + base + j);
        float4 o;
        o.x = (val[j]     - m2) * i2 * g4.x + b4.x;
        o.y = (val[j + 1] - m2) * i2 * g4.y + b4.y;
        o.z = (val[j + 2] - m2) * i2 * g4.z + b4.z;
        o.w = (val[j + 3] - m2) * i2 * g4.w + b4.w;
        *reinterpret_cast<float4*>(yp + base + j) = o;
    }
}

// scores from h via w2a; softmax over L; scale h in place; store probs
__global__ __launch_bounds__(256) void k_scores(
    float* __restrict__ h, const float* __restrict__ w2a,
    const float* __restrict__ c2, const float* __restrict__ attn_b,
    float* __restrict__ scores)
{
    const int bt = blockIdx.x;
    const int tid = threadIdx.x, wid = tid >> 6, lane = tid & 63;
    __shared__ float slog[nL];
    float* hrow = h + (size_t)bt * nLD;
    for (int l = wid; l < nL; l += 4) {
        const float* hp = hrow + l * nD;
        const float* wp = w2a + l * nD;
        float s = 0.f;
        for (int i = lane; i < nD; i += 64) s += hp[i] * wp[i];
#pragma unroll
        for (int off = 32; off > 0; off >>= 1) s += __shfl_down(s, off, 64);
        if (lane == 0) slog[l] = s + c2[l] + attn_b[0];
    }
    __syncthreads();
    float mx = -1e30f;
#pragma unroll
    for (int l = 0; l < nL; ++l) mx = fmaxf(mx, slog[l]);
    float den = 0.f;
#pragma unroll
    for (int l = 0; l < nL; ++l) den += __expf(slog[l] - mx);
    float rden = 1.f / den;
#pragma unroll
    for (int it = 0; it < 4; ++it) {
        int idx = tid * 4 + it * 1024;
        int l = idx >> 9;
        float s = __expf(slog[l] - mx) * rden;
        float4 v = *reinterpret_cast<float4*>(hrow + idx);
        v.x *= s; v.y *= s; v.z *= s; v.w *= s;
        *reinterpret_cast<float4*>(hrow + idx) = v;
    }
    if (tid < nL) scores[bt * nL + tid] = __expf(slog[tid] - mx) * rden;
}

// out = LN( wbuf + sum_l s_l * ff_b2[l] ) with ln_emb params
__global__ __launch_bounds__(256) void k_final(
    const float* __restrict__ wbuf, const float* __restrict__ scores,
    const float* __restrict__ ff_b2, const float* __restrict__ g,
    const float* __restrict__ bvec, float* __restrict__ out)
{
    const int bt = blockIdx.x;
    const int tid = threadIdx.x;
    __shared__ float ssc[nL];
    __shared__ float red[8];
    if (tid < nL) ssc[tid] = scores[bt * nL + tid];
    __syncthreads();
    const int e0 = tid * 4;
    float4 w = *reinterpret_cast<const float4*>(wbuf + (size_t)bt * nE + e0);
#pragma unroll
    for (int l = 0; l < nL; ++l) {
        float s = ssc[l];
        float4 b2 = *reinterpret_cast<const float4*>(ff_b2 + l * nE + e0);
        w.x += s * b2.x; w.y += s * b2.y; w.z += s * b2.z; w.w += s * b2.w;
    }
    float sum = w.x + w.y + w.z + w.w;
    float sq = w.x * w.x + w.y * w.y + w.z * w.z + w.w * w.w;
    int wid = tid >> 6, lane = tid & 63;
#pragma unroll
    for (int off = 32; off > 0; off >>= 1) {
        sum += __shfl_down(sum, off, 64); sq += __shfl_down(sq, off, 64);
    }
    if (lane == 0) { red[wid] = sum; red[4 + wid] = sq; }
    __syncthreads();
    sum = red[0] + red[1] + red[2] + red[3];
    sq  = red[4] + red[5] + red[6] + red[7];
    float mean = sum * (1.f / nE);
    float inv = rsqrtf(sq * (1.f / nE) - mean * mean + 1e-5f);
    float4 g4 = *reinterpret_cast<const float4*>(g + e0);
    float4 b4 = *reinterpret_cast<const float4*>(bvec + e0);
    float4 o;
    o.x = (w.x - mean) * inv * g4.x + b4.x;
    o.y = (w.y - mean) * inv * g4.y + b4.y;
    o.z = (w.z - mean) * inv * g4.z + b4.z;
    o.w = (w.w - mean) * inv * g4.w + b4.w;
    *reinterpret_cast<float4*>(out + (size_t)bt * nE + e0) = o;
}

extern "C" void kernel_launch(void* const* d_in, const int* in_sizes, int n_in,
                              void* d_out, int out_size, void* d_ws, size_t ws_size,
                              hipStream_t stream) {
    (void)in_sizes; (void)n_in; (void)out_size; (void)ws_size;
    const float* emb            = (const float*)d_in[0];
    const float* state_control  = (const float*)d_in[1];
    const float* input_influence= (const float*)d_in[2];
    const float* output_shaper  = (const float*)d_in[3];
    const float* glu_w          = (const float*)d_in[4];
    const float* glu_b          = (const float*)d_in[5];
    const float* e2s_w          = (const float*)d_in[6];
    const float* e2s_b          = (const float*)d_in[7];
    const float* ln_glu_g       = (const float*)d_in[8];
    const float* ln_glu_b       = (const float*)d_in[9];
    const float* ln_state_g     = (const float*)d_in[10];
    const float* ln_state_b     = (const float*)d_in[11];
    const float* ln_emb_g       = (const float*)d_in[12];
    const float* ln_emb_b       = (const float*)d_in[13];
    const float* ff_ln_g        = (const float*)d_in[14];
    const float* ff_ln_b        = (const float*)d_in[15];
    const float* ff_w1          = (const float*)d_in[16];
    const float* ff_b1          = (const float*)d_in[17];
    const float* ff_w2          = (const float*)d_in[18];
    const float* ff_b2          = (const float*)d_in[19];
    const float* attn_w         = (const float*)d_in[20];
    const float* attn_b         = (const float*)d_in[21];

    // workspace layout (~143 MB)
    char* ws = (char*)d_ws;
    float* tokens = (float*)ws;  ws += (size_t)nBT * nLD * 4;             // 67 MB (later: y, then wbuf)
    float* vbuf   = (float*)ws;  ws += (size_t)nBT * nLD * 4;             // 67 MB raw v (later: h)
    uint4* wswz   = (uint4*)ws;  ws += (size_t)nL * 8 * 8 * 16 * 64 * 16; // 8 MB packed B-frags
    float* sc_sum = (float*)ws;  ws += nLD * 4;
    float* ii_sum = (float*)ws;  ws += nLD * 4;
    float* os_sum = (float*)ws;  ws += nLD * 4;
    float* w2a    = (float*)ws;  ws += nLD * 4;
    float* c2     = (float*)ws;  ws += 256;
    float* scores = (float*)ws;  ws += (size_t)nBT * nL * 4;
    unsigned int* flags = (unsigned int*)ws; ws += nL * 8 * 4;
    float* wbuf = tokens;  // alias: tokens (y) dead after ff1 GEMM

    // precompute
    k_init<<<1, 64, 0, stream>>>(flags);
    k_pack2<<<nL * 64, 256, 0, stream>>>(glu_w, wswz);
    k_wdot<<<1024, 256, 0, stream>>>(state_control, nullptr, sc_sum, nLD, nD);
    k_wdot<<<1024, 256, 0, stream>>>(input_influence, nullptr, ii_sum, nLD, nD);
    k_wdot<<<1024, 256, 0, stream>>>(output_shaper, nullptr, os_sum, nLD, nD);
    k_wdot<<<1024, 256, 0, stream>>>(ff_w2, attn_w, w2a, nLD, nE);
    k_wdot<<<2, 256, 0, stream>>>(ff_b2, attn_w, c2, nL, nE);

    // tokens = emb @ e2s_w + e2s_b   [4096 x 4096], K=1024
    k_gemm<0><<<dim3(32, 32, 1), 256, 0, stream>>>(
        emb, nE, 0, e2s_w, nLD, 0, e2s_b, 0, tokens, nLD, 0, nBT, nLD, nE);

    // distributed recurrent scan -> raw v
    k_scan6<<<64, 512, 0, stream>>>(tokens, wswz, glu_b, sc_sum, ii_sum,
                                    ln_glu_g, ln_glu_b, ln_state_g, ln_state_b,
                                    vbuf, flags);

    // y = LN_ff(LN_state(v) * os_sum)  (into tokens buffer)
    k_y2<<<nBT * nL / 4, 256, 0, stream>>>(vbuf, os_sum,
                                           ln_state_g, ln_state_b,
                                           ff_ln_g, ff_ln_b, tokens);

    // h = GELU(y @ ff_w1 + ff_b1), per-layer batched  (into vbuf)
    k_gemm<1><<<dim3(4, 32, 8), 256, 0, stream>>>(
        tokens, nLD, nD, ff_w1, nD, (long long)nD * nD, ff_b1, nD,
        vbuf, nLD, nD, nBT, nD, nD);

    // scores + scale h in place
    k_scores<<<nBT, 256, 0, stream>>>(vbuf, w2a, c2, attn_b, scores);

    // weighted = (s*h) @ W2cat   [4096 x 1024], K=4096  (into wbuf=tokens)
    k_gemm<0><<<dim3(8, 32, 1), 256, 0, stream>>>(
        vbuf, nLD, 0, ff_w2, nE, 0, nullptr, 0, wbuf, nE, 0, nBT, nE, nLD);

    // out = LN(weighted + sum_l s_l*ff_b2[l])
    k_final<<<nBT, 256, 0, stream>>>(wbuf, scores, ff_b2, ln_emb_g, ln_emb_b, (float*)d_out);
}

// Round 8
// 3120.179 us; speedup vs baseline: 5.3360x; 1.1638x over previous
//
#include <hip/hip_runtime.h>
#include <hip/hip_bf16.h>
#include <math.h>

// Fixed problem dims
static constexpr int nB = 8, nT = 512, nE = 1024, nL = 8, nD = 512;
static constexpr int nBT = nB * nT;   // 4096 rows (b,t)
static constexpr int nLD = nL * nD;   // 4096

typedef __attribute__((ext_vector_type(8))) short short8v;  // 8 bf16 (4 VGPRs)
typedef __attribute__((ext_vector_type(4))) float f32x4;
typedef __attribute__((ext_vector_type(4))) unsigned int u32x4;  // asm-safe

__device__ __forceinline__ unsigned short f2bf(float f) {
    unsigned int u = __float_as_uint(f);
    return (unsigned short)((u + 0x7fffu + ((u >> 16) & 1u)) >> 16);  // RNE
}
__device__ __forceinline__ float bfu2f(unsigned short u) {
    return __uint_as_float(((unsigned int)u) << 16);
}
__device__ __forceinline__ float gelu_f(float x) {
    return 0.5f * x * (1.0f + erff(x * 0.70710678118654752f));  // exact GELU
}

// dst[r] = sum_i src[r,i] * (w ? w[i] : 1)
__global__ __launch_bounds__(256) void k_wdot(const float* __restrict__ src,
                                              const float* __restrict__ w,
                                              float* __restrict__ dst,
                                              int rows, int rowlen) {
    int row = blockIdx.x * 4 + (threadIdx.x >> 6);
    if (row >= rows) return;
    int lane = threadIdx.x & 63;
    const float* p = src + (size_t)row * rowlen;
    float s = 0.f;
    if (w) { for (int i = lane; i < rowlen; i += 64) s += p[i] * w[i]; }
    else   { for (int i = lane; i < rowlen; i += 64) s += p[i]; }
#pragma unroll
    for (int off = 32; off > 0; off >>= 1) s += __shfl_down(s, off, 64);
    if (lane == 0) dst[row] = s;
}

// zero all record tags (must run each launch: stale tags from the previous
// timed replay alias valid step numbers)
__global__ __launch_bounds__(256) void k_init2(unsigned int* recs) {
    int i = blockIdx.x * 256 + threadIdx.x;   // 16384 records
    if (i < 2 * nL * nB * 128)
        __hip_atomic_store(recs + i * 4 + 3, 0u,
                           __ATOMIC_RELAXED, __HIP_MEMORY_SCOPE_AGENT);
}

// Pack glu_w into MFMA B-fragment layout with INTERLEAVED a/g columns:
// frag col j: j=2u -> a-col q*64+w*8+u ; j=2u+1 -> g-col 512+q*64+w*8+u.
// dst[((l*8+q)*8+w)*16+kt][lane]: pairs p -> k = 32kt+8*(lane>>4)+2p(+1).
__global__ __launch_bounds__(256) void k_pack2(const float* __restrict__ src,
                                               uint4* __restrict__ dst) {
    const int blk = blockIdx.x;            // l*64 + q*8 + w   (512 blocks)
    const int w = blk & 7, q = (blk >> 3) & 7, l = blk >> 6;
    const float* wl = src + (size_t)l * nD * 1024;
    for (int i = threadIdx.x; i < 16 * 64; i += 256) {
        const int kt = i >> 6, ln = i & 63;
        const int j = ln & 15, g = ln >> 4;
        const int u = j >> 1;
        const int col = (j & 1) ? (512 + q * 64 + w * 8 + u)
                                : (q * 64 + w * 8 + u);
        const int k0 = 32 * kt + 8 * g;
        unsigned pr[4];
#pragma unroll
        for (int p = 0; p < 4; ++p) {
            float a = wl[(size_t)(k0 + 2 * p) * 1024 + col];
            float c = wl[(size_t)(k0 + 2 * p + 1) * 1024 + col];
            pr[p] = (unsigned)f2bf(a) | ((unsigned)f2bf(c) << 16);
        }
        dst[((((size_t)l * 8 + q) * 8 + w) * 16 + kt) * 64 + ln] =
            make_uint4(pr[0], pr[1], pr[2], pr[3]);
    }
}

// C[m,n] = act( sum_k A[m,k]*B[k,n] + bias[n] ), 128x128 tile, BK=16, fp32
template<int ACT>
__global__ __launch_bounds__(256) void k_gemm(
    const float* __restrict__ A, int lda, long long sA,
    const float* __restrict__ Bm, int ldb, long long sB,
    const float* __restrict__ bias, long long sBias,
    float* __restrict__ C, int ldc, long long sC,
    int M, int N, int K)
{
    A  += (size_t)blockIdx.z * sA;
    Bm += (size_t)blockIdx.z * sB;
    C  += (size_t)blockIdx.z * sC;
    const float* biasp = bias ? bias + (size_t)blockIdx.z * sBias : nullptr;

    __shared__ __align__(16) float As[16][128];
    __shared__ __align__(16) float Bs[16][128];
    const int tid = threadIdx.x;
    const int tx = tid & 15, ty = tid >> 4;
    const int bm = blockIdx.y * 128, bn = blockIdx.x * 128;

    float acc[8][8];
#pragma unroll
    for (int i = 0; i < 8; ++i)
#pragma unroll
        for (int j = 0; j < 8; ++j) acc[i][j] = 0.f;

    const int arow = tid >> 1, ac8 = (tid & 1) * 8;
    const int brow = tid >> 4, bc8 = (tid & 15) * 8;

    for (int kt = 0; kt < K; kt += 16) {
        float4 a0 = *reinterpret_cast<const float4*>(A + (size_t)(bm + arow) * lda + kt + ac8);
        float4 a1 = *reinterpret_cast<const float4*>(A + (size_t)(bm + arow) * lda + kt + ac8 + 4);
        float4 b0 = *reinterpret_cast<const float4*>(Bm + (size_t)(kt + brow) * ldb + bn + bc8);
        float4 b1 = *reinterpret_cast<const float4*>(Bm + (size_t)(kt + brow) * ldb + bn + bc8 + 4);
        __syncthreads();
        As[ac8 + 0][arow] = a0.x; As[ac8 + 1][arow] = a0.y;
        As[ac8 + 2][arow] = a0.z; As[ac8 + 3][arow] = a0.w;
        As[ac8 + 4][arow] = a1.x; As[ac8 + 5][arow] = a1.y;
        As[ac8 + 6][arow] = a1.z; As[ac8 + 7][arow] = a1.w;
        *reinterpret_cast<float4*>(&Bs[brow][bc8]) = b0;
        *reinterpret_cast<float4*>(&Bs[brow][bc8 + 4]) = b1;
        __syncthreads();
#pragma unroll
        for (int kk = 0; kk < 16; ++kk) {
            float ar[8], br[8];
            *reinterpret_cast<float4*>(&ar[0]) = *reinterpret_cast<const float4*>(&As[kk][ty * 4]);
            *reinterpret_cast<float4*>(&ar[4]) = *reinterpret_cast<const float4*>(&As[kk][64 + ty * 4]);
            *reinterpret_cast<float4*>(&br[0]) = *reinterpret_cast<const float4*>(&Bs[kk][tx * 4]);
            *reinterpret_cast<float4*>(&br[4]) = *reinterpret_cast<const float4*>(&Bs[kk][64 + tx * 4]);
#pragma unroll
            for (int i = 0; i < 8; ++i)
#pragma unroll
                for (int j = 0; j < 8; ++j) acc[i][j] = fmaf(ar[i], br[j], acc[i][j]);
        }
    }
#pragma unroll
    for (int i = 0; i < 8; ++i) {
        int r = bm + (i >> 2) * 64 + ty * 4 + (i & 3);
#pragma unroll
        for (int jh = 0; jh < 2; ++jh) {
            int cb = bn + jh * 64 + tx * 4;
            float4 v = make_float4(acc[i][jh * 4 + 0], acc[i][jh * 4 + 1],
                                   acc[i][jh * 4 + 2], acc[i][jh * 4 + 3]);
            if (biasp) { v.x += biasp[cb]; v.y += biasp[cb + 1]; v.z += biasp[cb + 2]; v.w += biasp[cb + 3]; }
            if (ACT == 1) { v.x = gelu_f(v.x); v.y = gelu_f(v.y); v.z = gelu_f(v.z); v.w = gelu_f(v.w); }
            *reinterpret_cast<float4*>(C + (size_t)r * ldc + cb) = v;
        }
    }
}

// ---------------------------------------------------------------------------
// Scan v3: tag-in-data exchange. Record (16B, single dwordx4 sc0 sc1 store):
//   j=0: {v6 bf16 (dims w*8..+5), tag}   j=1: {v2 bf16 (dims +6,+7), S, Q, tag}
// recs[slot=t&1][l][b][idx=q*16+w*2+j]. Consumer: ONE poll load round gets
// validity + payload + LN stats. No flags, no vmcnt drains on critical path.
// ---------------------------------------------------------------------------
__global__ __launch_bounds__(512, 1) void k_scan7(
    const float* __restrict__ tokens,      // [B,T,L,D]
    const uint4* __restrict__ wswz,        // packed B-fragments (interleaved)
    const float* __restrict__ glu_b,       // [L,2D]
    const float* __restrict__ sc_sum, const float* __restrict__ ii_sum,
    const float* __restrict__ ln_glu_g, const float* __restrict__ ln_glu_b,
    const float* __restrict__ ln_state_g, const float* __restrict__ ln_state_b,
    float* __restrict__ vout,              // [B,T,L,D] raw v (fp32, plain)
    unsigned int* __restrict__ recs)
{
    const int l = blockIdx.x & 7, q = blockIdx.x >> 3;
    const int tid = threadIdx.x, w = tid >> 6, lane = tid & 63;
    const int b = w;  // wave = batch

    __shared__ __align__(16) unsigned hn_pk[8][260];       // bf16 pairs, padded
    __shared__ __align__(16) unsigned zbuf[4];
    __shared__ __align__(16) unsigned short vrow[8][512];  // consumer v (bf16)
    __shared__ __align__(16) unsigned short vstage[8][64]; // producer stage
    __shared__ __align__(16) float vsq[8][8][2];           // [b][w]{S,Q}

    // resident B-fragments: wave w = n-tile w, 16 k-tiles
    uint4 wr[16];
    {
        const uint4* wp = wswz + ((((size_t)l * 8 + q) * 8 + w) * 16) * 64 + lane;
#pragma unroll
        for (int kt = 0; kt < 16; ++kt) wr[kt] = wp[kt * 64];
    }
    const int d0 = lane * 8;
    float P_sc[8], P_ii[8], P_gg[8], P_gb[8], P_sg[8], P_sb[8];
#pragma unroll
    for (int j = 0; j < 8; j += 4) {
        *reinterpret_cast<float4*>(&P_sc[j]) = *reinterpret_cast<const float4*>(sc_sum + l * nD + d0 + j);
        *reinterpret_cast<float4*>(&P_ii[j]) = *reinterpret_cast<const float4*>(ii_sum + l * nD + d0 + j);
        *reinterpret_cast<float4*>(&P_gg[j]) = *reinterpret_cast<const float4*>(ln_glu_g + d0 + j);
        *reinterpret_cast<float4*>(&P_gb[j]) = *reinterpret_cast<const float4*>(ln_glu_b + d0 + j);
        *reinterpret_cast<float4*>(&P_sg[j]) = *reinterpret_cast<const float4*>(ln_state_g + d0 + j);
        *reinterpret_cast<float4*>(&P_sb[j]) = *reinterpret_cast<const float4*>(ln_state_b + d0 + j);
    }
    const int cu = (lane & 15) >> 1;
    const int mycol = (lane & 1) ? (512 + q * 64 + w * 8 + cu)
                                 : (q * 64 + w * 8 + cu);
    const float bias_c = glu_b[l * 1024 + mycol];
    const int vcol = q * 64 + w * 8 + cu;

    if (tid < 4) zbuf[tid] = 0u;

    const float* tokp = tokens + ((size_t)b * nT * nL + l) * nD + d0;

    // A-fragment source: frag row (lane&15) = batch, rows 8-15 -> zeros
    const unsigned* afp; int astep;
    {
        int bb = lane & 15, g = lane >> 4;
        if (bb < 8) { afp = &hn_pk[bb][g * 4]; astep = 16; }
        else        { afp = &zbuf[0];          astep = 0;  }
    }
    __syncthreads();

    float4 tk0 = *reinterpret_cast<const float4*>(tokp);
    float4 tk1 = *reinterpret_cast<const float4*>(tokp + 4);

    for (int t = 0; t < nT; ++t) {
        float tk[8] = {tk0.x, tk0.y, tk0.z, tk0.w, tk1.x, tk1.y, tk1.z, tk1.w};
        float h[8];
        if (t > 0) {
            // ---- poll: the data IS the flag (one LLC round trip) ----
            const unsigned* rp = recs + ((((size_t)((t - 1) & 1) * nL + l) * nB + b) * 128) * 4;
            const unsigned* pa = rp + lane * 4;
            const unsigned* pb = rp + (lane + 64) * 4;
            u32x4 ra, rb;
            int ok;
            do {
                asm volatile(
                    "global_load_dwordx4 %0, %2, off sc0 sc1\n\t"
                    "global_load_dwordx4 %1, %3, off sc0 sc1\n\t"
                    "s_waitcnt vmcnt(0)"
                    : "=&v"(ra), "=&v"(rb)
                    : "v"(pa), "v"(pb)
                    : "memory");
                ok = (ra[3] == (unsigned)t) && (rb[3] == (unsigned)t);
            } while (!__all(ok));

            // embedded LN stats (odd lanes carry j=1 records with S,Q)
            float S = 0.f, Q = 0.f;
            if (lane & 1) {
                S = __uint_as_float(ra[1]) + __uint_as_float(rb[1]);
                Q = __uint_as_float(ra[2]) + __uint_as_float(rb[2]);
            }
#pragma unroll
            for (int o = 32; o > 0; o >>= 1) { S += __shfl_xor(S, o, 64); Q += __shfl_xor(Q, o, 64); }
            const float mv = S * (1.f / nD);
            const float iv = rsqrtf(Q * (1.f / nD) - mv * mv + 1e-5f);

            // redistribute payloads into vrow[b] (wave-local LDS region)
            {
                const int ia = lane, ib2 = lane + 64;
                const int qa = ia >> 4, wa = (ia >> 1) & 7, ja = ia & 1;
                const int qb2 = ib2 >> 4, wb2 = (ib2 >> 1) & 7;
                unsigned* da = reinterpret_cast<unsigned*>(&vrow[b][qa * 64 + wa * 8 + ja * 6]);
                unsigned* db = reinterpret_cast<unsigned*>(&vrow[b][qb2 * 64 + wb2 * 8 + ja * 6]);
                if (!ja) {
                    da[0] = ra[0]; da[1] = ra[1]; da[2] = ra[2];
                    db[0] = rb[0]; db[1] = rb[1]; db[2] = rb[2];
                } else {
                    da[0] = ra[0];
                    db[0] = rb[0];
                }
            }
            asm volatile("s_waitcnt lgkmcnt(0)" ::: "memory");
            __builtin_amdgcn_sched_barrier(0);
            uint4 pv = *reinterpret_cast<const uint4*>(&vrow[b][lane * 8]);
            float vv[8];
            vv[0] = bfu2f((unsigned short)(pv.x & 0xffffu));
            vv[1] = bfu2f((unsigned short)(pv.x >> 16));
            vv[2] = bfu2f((unsigned short)(pv.y & 0xffffu));
            vv[3] = bfu2f((unsigned short)(pv.y >> 16));
            vv[4] = bfu2f((unsigned short)(pv.z & 0xffffu));
            vv[5] = bfu2f((unsigned short)(pv.z >> 16));
            vv[6] = bfu2f((unsigned short)(pv.w & 0xffffu));
            vv[7] = bfu2f((unsigned short)(pv.w >> 16));
#pragma unroll
            for (int j = 0; j < 8; ++j) {
                float st = (vv[j] - mv) * iv * P_sg[j] + P_sb[j];
                h[j] = st * P_sc[j] + tk[j] * P_ii[j];
            }
        } else {
#pragma unroll
            for (int j = 0; j < 8; ++j) h[j] = tk[j] * P_ii[j];
        }

        // token prefetch for t+1 (in flight across barriers)
        if (t + 1 < nT) {
            tk0 = *reinterpret_cast<const float4*>(tokp + (size_t)(t + 1) * nLD);
            tk1 = *reinterpret_cast<const float4*>(tokp + (size_t)(t + 1) * nLD + 4);
        }

        // LN(h) over the wave's 512 dims
        float S = 0.f, Q = 0.f;
#pragma unroll
        for (int j = 0; j < 8; ++j) { S += h[j]; Q += h[j] * h[j]; }
#pragma unroll
        for (int o = 32; o > 0; o >>= 1) { S += __shfl_xor(S, o, 64); Q += __shfl_xor(Q, o, 64); }
        const float mh = S * (1.f / nD);
        const float ih = rsqrtf(Q * (1.f / nD) - mh * mh + 1e-5f);
        unsigned pr[4];
#pragma unroll
        for (int p = 0; p < 4; ++p) {
            float a0 = (h[2 * p]     - mh) * ih * P_gg[2 * p]     + P_gb[2 * p];
            float a1 = (h[2 * p + 1] - mh) * ih * P_gg[2 * p + 1] + P_gb[2 * p + 1];
            pr[p] = (unsigned)f2bf(a0) | ((unsigned)f2bf(a1) << 16);
        }
        *reinterpret_cast<uint4*>(&hn_pk[b][lane * 4]) = make_uint4(pr[0], pr[1], pr[2], pr[3]);

        // BAR1: hn ready (LDS only)
        asm volatile("s_waitcnt lgkmcnt(0)" ::: "memory");
        __builtin_amdgcn_s_barrier();
        __builtin_amdgcn_sched_barrier(0);

        // MFMA: rows = batches, cols = wave's interleaved 16-col tile
        f32x4 acc0 = {0.f, 0.f, 0.f, 0.f}, acc1 = {0.f, 0.f, 0.f, 0.f};
#pragma unroll
        for (int kt = 0; kt < 8; ++kt) {
            short8v a0 = *reinterpret_cast<const short8v*>(afp + (2 * kt) * astep);
            short8v a1 = *reinterpret_cast<const short8v*>(afp + (2 * kt + 1) * astep);
            acc0 = __builtin_amdgcn_mfma_f32_16x16x32_bf16(
                a0, __builtin_bit_cast(short8v, wr[2 * kt]), acc0, 0, 0, 0);
            acc1 = __builtin_amdgcn_mfma_f32_16x16x32_bf16(
                a1, __builtin_bit_cast(short8v, wr[2 * kt + 1]), acc1, 0, 0, 0);
        }

        // GLU in-register; v to vout (plain fp32) + vstage (bf16) + partials
        float x[4], y[4];
#pragma unroll
        for (int i = 0; i < 4; ++i) x[i] = acc0[i] + acc1[i] + bias_c;
#pragma unroll
        for (int i = 0; i < 4; ++i) y[i] = __shfl_xor(x[i], 1, 64);
        float sv[4], sq[4];
        const int r0 = (lane >> 4) * 4;
        const bool prod = (lane < 32) && !(lane & 1);
#pragma unroll
        for (int i = 0; i < 4; ++i) {
            float v = x[i] / (1.f + __expf(-y[i]));
            sv[i] = prod ? v : 0.f;
            sq[i] = prod ? v * v : 0.f;
            if (prod) {
                vout[(((size_t)(r0 + i) * nT + t) * nL + l) * nD + vcol] = v;
                vstage[r0 + i][w * 8 + cu] = f2bf(v);
            }
        }
        // per-(batch, wave) partial S,Q over the wave's 8 dims
#pragma unroll
        for (int i = 0; i < 4; ++i) {
            sv[i] += __shfl_xor(sv[i], 2, 64); sq[i] += __shfl_xor(sq[i], 2, 64);
            sv[i] += __shfl_xor(sv[i], 4, 64); sq[i] += __shfl_xor(sq[i], 4, 64);
            sv[i] += __shfl_xor(sv[i], 8, 64); sq[i] += __shfl_xor(sq[i], 8, 64);
        }
        if (lane == 0 || lane == 16) {
#pragma unroll
            for (int i = 0; i < 4; ++i) {
                vsq[r0 + i][w][0] = sv[i];
                vsq[r0 + i][w][1] = sq[i];
            }
        }

        // BAR2: vstage/vsq visible (LDS only; vout stores stay in flight)
        asm volatile("s_waitcnt lgkmcnt(0)" ::: "memory");
        __builtin_amdgcn_s_barrier();
        __builtin_amdgcn_sched_barrier(0);

        // builders: 128 threads emit this WG's records {payload, tag=t+1}
        if (tid < 128) {
            const int bb = tid >> 4, wb = (tid >> 1) & 7, jb = tid & 1;
            const unsigned* vp = reinterpret_cast<const unsigned*>(&vstage[bb][wb * 8]);
            u32x4 rec;
            if (!jb) { rec[0] = vp[0]; rec[1] = vp[1]; rec[2] = vp[2]; }
            else {
                rec[0] = vp[3];
                rec[1] = __float_as_uint(vsq[bb][wb][0]);
                rec[2] = __float_as_uint(vsq[bb][wb][1]);
            }
            rec[3] = (unsigned)(t + 1);
            unsigned* dst = recs + (((((size_t)(t & 1) * nL + l) * nB + bb) * 128)
                                    + q * 16 + wb * 2 + jb) * 4;
            asm volatile("global_store_dwordx4 %0, %1, off sc0 sc1"
                         :: "v"(dst), "v"(rec) : "memory");
        }
        // no drain: tag rides with payload; next poll provides the sync
    }
}

// y = LN_ff( LN_state(raw v) * os_sum[l] ); stats computed from the row
__global__ __launch_bounds__(256) void k_y2(
    const float* __restrict__ vout, const float* __restrict__ os_sum,
    const float* __restrict__ lsg, const float* __restrict__ lsb,
    const float* __restrict__ fg, const float* __restrict__ fb,
    float* __restrict__ y)
{
    const int row = blockIdx.x * 4 + (threadIdx.x >> 6);   // over B*T*L
    const int lane = threadIdx.x & 63;
    const int l = row & 7;

    const float* vp = vout + (size_t)row * nD;
    const int base = lane * 8;
    float vv[8];
    *reinterpret_cast<float4*>(&vv[0]) = *reinterpret_cast<const float4*>(vp + base);
    *reinterpret_cast<float4*>(&vv[4]) = *reinterpret_cast<const float4*>(vp + base + 4);
    float S = 0.f, Q = 0.f;
#pragma unroll
    for (int j = 0; j < 8; ++j) { S += vv[j]; Q += vv[j] * vv[j]; }
#pragma unroll
    for (int o = 32; o > 0; o >>= 1) { S += __shfl_xor(S, o, 64); Q += __shfl_xor(Q, o, 64); }
    const float mv = S * (1.f / nD);
    const float iv = rsqrtf(Q * (1.f / nD) - mv * mv + 1e-5f);

    const float* op = os_sum + l * nD;
    float val[8];
    float s2 = 0.f, q2 = 0.f;
#pragma unroll
    for (int j = 0; j < 8; j += 4) {
        float4 o4 = *reinterpret_cast<const float4*>(op + base + j);
        float4 g4 = *reinterpret_cast<const float4*>(lsg + base + j);
        float4 b4 = *reinterpret_cast<const float4*>(lsb + base + j);
        val[j]     = ((vv[j]     - mv) * iv * g4.x + b4.x) * o4.x;
        val[j + 1] = ((vv[j + 1] - mv) * iv * g4.y + b4.y) * o4.y;
        val[j + 2] = ((vv[j + 2] - mv) * iv * g4.z + b4.z) * o4.z;
        val[j + 3] = ((vv[j + 3] - mv) * iv * g4.w + b4.w) * o4.w;
    }
#pragma unroll
    for (int j = 0; j < 8; ++j) { s2 += val[j]; q2 += val[j] * val[j]; }
#pragma unroll
    for (int o = 32; o > 0; o >>= 1) { s2 += __shfl_xor(s2, o, 64); q2 += __shfl_xor(q2, o, 64); }
    const float m2 = s2 * (1.f / nD);
    const float i2 = rsqrtf(q2 * (1.f / nD) - m2 * m2 + 1e-5f);
    const float* gp = fg + l * nD;
    const float* bp = fb + l * nD;
    float* yp = y + (size_t)row * nD;
#pragma unroll
    for (int j = 0; j < 8; j += 4) {
        float4 g4 = *reinterpret_cast<const float4*>(gp + base + j);
        float4 b4 = *reinterpret_cast<const float4*>(bp + base + j);
        float4 o;
        o.x = (val[j]     - m2) * i2 * g4.x + b4.x;
        o.y = (val[j + 1] - m2) * i2 * g4.y + b4.y;
        o.z = (val[j + 2] - m2) * i2 * g4.z + b4.z;
        o.w = (val[j + 3] - m2) * i2 * g4.w + b4.w;
        *reinterpret_cast<float4*>(yp + base + j) = o;
    }
}

// scores from h via w2a; softmax over L; scale h in place; store probs
__global__ __launch_bounds__(256) void k_scores(
    float* __restrict__ h, const float* __restrict__ w2a,
    const float* __restrict__ c2, const float* __restrict__ attn_b,
    float* __restrict__ scores)
{
    const int bt = blockIdx.x;
    const int tid = threadIdx.x, wid = tid >> 6, lane = tid & 63;
    __shared__ float slog[nL];
    float* hrow = h + (size_t)bt * nLD;
    for (int l = wid; l < nL; l += 4) {
        const float* hp = hrow + l * nD;
        const float* wp = w2a + l * nD;
        float s = 0.f;
        for (int i = lane; i < nD; i += 64) s += hp[i] * wp[i];
#pragma unroll
        for (int off = 32; off > 0; off >>= 1) s += __shfl_down(s, off, 64);
        if (lane == 0) slog[l] = s + c2[l] + attn_b[0];
    }
    __syncthreads();
    float mx = -1e30f;
#pragma unroll
    for (int l = 0; l < nL; ++l) mx = fmaxf(mx, slog[l]);
    float den = 0.f;
#pragma unroll
    for (int l = 0; l < nL; ++l) den += __expf(slog[l] - mx);
    float rden = 1.f / den;
#pragma unroll
    for (int it = 0; it < 4; ++it) {
        int idx = tid * 4 + it * 1024;
        int l = idx >> 9;
        float s = __expf(slog[l] - mx) * rden;
        float4 v = *reinterpret_cast<float4*>(hrow + idx);
        v.x *= s; v.y *= s; v.z *= s; v.w *= s;
        *reinterpret_cast<float4*>(hrow + idx) = v;
    }
    if (tid < nL) scores[bt * nL + tid] = __expf(slog[tid] - mx) * rden;
}

// out = LN( wbuf + sum_l s_l * ff_b2[l] ) with ln_emb params
__global__ __launch_bounds__(256) void k_final(
    const float* __restrict__ wbuf, const float* __restrict__ scores,
    const float* __restrict__ ff_b2, const float* __restrict__ g,
    const float* __restrict__ bvec, float* __restrict__ out)
{
    const int bt = blockIdx.x;
    const int tid = threadIdx.x;
    __shared__ float ssc[nL];
    __shared__ float red[8];
    if (tid < nL) ssc[tid] = scores[bt * nL + tid];
    __syncthreads();
    const int e0 = tid * 4;
    float4 w = *reinterpret_cast<const float4*>(wbuf + (size_t)bt * nE + e0);
#pragma unroll
    for (int l = 0; l < nL; ++l) {
        float s = ssc[l];
        float4 b2 = *reinterpret_cast<const float4*>(ff_b2 + l * nE + e0);
        w.x += s * b2.x; w.y += s * b2.y; w.z += s * b2.z; w.w += s * b2.w;
    }
    float sum = w.x + w.y + w.z + w.w;
    float sq = w.x * w.x + w.y * w.y + w.z * w.z + w.w * w.w;
    int wid = tid >> 6, lane = tid & 63;
#pragma unroll
    for (int off = 32; off > 0; off >>= 1) {
        sum += __shfl_down(sum, off, 64); sq += __shfl_down(sq, off, 64);
    }
    if (lane == 0) { red[wid] = sum; red[4 + wid] = sq; }
    __syncthreads();
    sum = red[0] + red[1] + red[2] + red[3];
    sq  = red[4] + red[5] + red[6] + red[7];
    float mean = sum * (1.f / nE);
    float inv = rsqrtf(sq * (1.f / nE) - mean * mean + 1e-5f);
    float4 g4 = *reinterpret_cast<const float4*>(g + e0);
    float4 b4 = *reinterpret_cast<const float4*>(bvec + e0);
    float4 o;
    o.x = (w.x - mean) * inv * g4.x + b4.x;
    o.y = (w.y - mean) * inv * g4.y + b4.y;
    o.z = (w.z - mean) * inv * g4.z + b4.z;
    o.w = (w.w - mean) * inv * g4.w + b4.w;
    *reinterpret_cast<float4*>(out + (size_t)bt * nE + e0) = o;
}

extern "C" void kernel_launch(void* const* d_in, const int* in_sizes, int n_in,
                              void* d_out, int out_size, void* d_ws, size_t ws_size,
                              hipStream_t stream) {
    (void)in_sizes; (void)n_in; (void)out_size; (void)ws_size;
    const float* emb            = (const float*)d_in[0];
    const float* state_control  = (const float*)d_in[1];
    const float* input_influence= (const float*)d_in[2];
    const float* output_shaper  = (const float*)d_in[3];
    const float* glu_w          = (const float*)d_in[4];
    const float* glu_b          = (const float*)d_in[5];
    const float* e2s_w          = (const float*)d_in[6];
    const float* e2s_b          = (const float*)d_in[7];
    const float* ln_glu_g       = (const float*)d_in[8];
    const float* ln_glu_b       = (const float*)d_in[9];
    const float* ln_state_g     = (const float*)d_in[10];
    const float* ln_state_b     = (const float*)d_in[11];
    const float* ln_emb_g       = (const float*)d_in[12];
    const float* ln_emb_b       = (const float*)d_in[13];
    const float* ff_ln_g        = (const float*)d_in[14];
    const float* ff_ln_b        = (const float*)d_in[15];
    const float* ff_w1          = (const float*)d_in[16];
    const float* ff_b1          = (const float*)d_in[17];
    const float* ff_w2          = (const float*)d_in[18];
    const float* ff_b2          = (const float*)d_in[19];
    const float* attn_w         = (const float*)d_in[20];
    const float* attn_b         = (const float*)d_in[21];

    // workspace layout (~144 MB)
    char* ws = (char*)d_ws;
    float* tokens = (float*)ws;  ws += (size_t)nBT * nLD * 4;             // 67 MB (later: y, then wbuf)
    float* vbuf   = (float*)ws;  ws += (size_t)nBT * nLD * 4;             // 67 MB raw v (later: h)
    uint4* wswz   = (uint4*)ws;  ws += (size_t)nL * 8 * 8 * 16 * 64 * 16; // 8 MB packed B-frags
    unsigned int* recs = (unsigned int*)ws; ws += (size_t)2 * nL * nB * 128 * 16;  // 256 KB
    float* sc_sum = (float*)ws;  ws += nLD * 4;
    float* ii_sum = (float*)ws;  ws += nLD * 4;
    float* os_sum = (float*)ws;  ws += nLD * 4;
    float* w2a    = (float*)ws;  ws += nLD * 4;
    float* c2     = (float*)ws;  ws += 256;
    float* scores = (float*)ws;  ws += (size_t)nBT * nL * 4;
    float* wbuf = tokens;  // alias: tokens (y) dead after ff1 GEMM

    // precompute
    k_init2<<<64, 256, 0, stream>>>(recs);
    k_pack2<<<nL * 64, 256, 0, stream>>>(glu_w, wswz);
    k_wdot<<<1024, 256, 0, stream>>>(state_control, nullptr, sc_sum, nLD, nD);
    k_wdot<<<1024, 256, 0, stream>>>(input_influence, nullptr, ii_sum, nLD, nD);
    k_wdot<<<1024, 256, 0, stream>>>(output_shaper, nullptr, os_sum, nLD, nD);
    k_wdot<<<1024, 256, 0, stream>>>(ff_w2, attn_w, w2a, nLD, nE);
    k_wdot<<<2, 256, 0, stream>>>(ff_b2, attn_w, c2, nL, nE);

    // tokens = emb @ e2s_w + e2s_b   [4096 x 4096], K=1024
    k_gemm<0><<<dim3(32, 32, 1), 256, 0, stream>>>(
        emb, nE, 0, e2s_w, nLD, 0, e2s_b, 0, tokens, nLD, 0, nBT, nLD, nE);

    // distributed recurrent scan -> raw v
    k_scan7<<<64, 512, 0, stream>>>(tokens, wswz, glu_b, sc_sum, ii_sum,
                                    ln_glu_g, ln_glu_b, ln_state_g, ln_state_b,
                                    vbuf, recs);

    // y = LN_ff(LN_state(v) * os_sum)  (into tokens buffer)
    k_y2<<<nBT * nL / 4, 256, 0, stream>>>(vbuf, os_sum,
                                           ln_state_g, ln_state_b,
                                           ff_ln_g, ff_ln_b, tokens);

    // h = GELU(y @ ff_w1 + ff_b1), per-layer batched  (into vbuf)
    k_gemm<1><<<dim3(4, 32, 8), 256, 0, stream>>>(
        tokens, nLD, nD, ff_w1, nD, (long long)nD * nD, ff_b1, nD,
        vbuf, nLD, nD, nBT, nD, nD);

    // scores + scale h in place
    k_scores<<<nBT, 256, 0, stream>>>(vbuf, w2a, c2, attn_b, scores);

    // weighted = (s*h) @ W2cat   [4096 x 1024], K=4096  (into wbuf=tokens)
    k_gemm<0><<<dim3(8, 32, 1), 256, 0, stream>>>(
        vbuf, nLD, 0, ff_w2, nE, 0, nullptr, 0, wbuf, nE, 0, nBT, nE, nLD);

    // out = LN(weighted + sum_l s_l*ff_b2[l])
    k_final<<<nBT, 256, 0, stream>>>(wbuf, scores, ff_b2, ln_emb_g, ln_emb_b, (float*)d_out);
}

// Round 9
// 2172.158 us; speedup vs baseline: 7.6649x; 1.4364x over previous
//
#include <hip/hip_runtime.h>
#include <hip/hip_bf16.h>
#include <math.h>

// Fixed problem dims
static constexpr int nB = 8, nT = 512, nE = 1024, nL = 8, nD = 512;
static constexpr int nBT = nB * nT;   // 4096 rows (b,t)
static constexpr int nLD = nL * nD;   // 4096

typedef __attribute__((ext_vector_type(8))) short short8v;  // 8 bf16 (4 VGPRs)
typedef __attribute__((ext_vector_type(4))) float f32x4;
typedef __attribute__((ext_vector_type(4))) unsigned int u32x4;  // asm-safe

__device__ __forceinline__ unsigned short f2bf(float f) {
    unsigned int u = __float_as_uint(f);
    return (unsigned short)((u + 0x7fffu + ((u >> 16) & 1u)) >> 16);  // RNE
}
__device__ __forceinline__ float bfu2f(unsigned short u) {
    return __uint_as_float(((unsigned int)u) << 16);
}
__device__ __forceinline__ float gelu_f(float x) {
    return 0.5f * x * (1.0f + erff(x * 0.70710678118654752f));  // exact GELU
}

// dst[r] = sum_i src[r,i] * (w ? w[i] : 1)
__global__ __launch_bounds__(256) void k_wdot(const float* __restrict__ src,
                                              const float* __restrict__ w,
                                              float* __restrict__ dst,
                                              int rows, int rowlen) {
    int row = blockIdx.x * 4 + (threadIdx.x >> 6);
    if (row >= rows) return;
    int lane = threadIdx.x & 63;
    const float* p = src + (size_t)row * rowlen;
    float s = 0.f;
    if (w) { for (int i = lane; i < rowlen; i += 64) s += p[i] * w[i]; }
    else   { for (int i = lane; i < rowlen; i += 64) s += p[i]; }
#pragma unroll
    for (int off = 32; off > 0; off >>= 1) s += __shfl_down(s, off, 64);
    if (lane == 0) dst[row] = s;
}

// zero all record tags (must run each launch: stale tags from the previous
// timed replay alias valid step numbers)
__global__ __launch_bounds__(256) void k_init2(unsigned int* recs) {
    int i = blockIdx.x * 256 + threadIdx.x;   // 16384 records
    if (i < 2 * nL * nB * 128)
        __hip_atomic_store(recs + i * 4 + 3, 0u,
                           __ATOMIC_RELAXED, __HIP_MEMORY_SCOPE_AGENT);
}

// flat fp32 -> bf16 cast
__global__ __launch_bounds__(256) void k_cast(const float* __restrict__ s,
                                              unsigned short* __restrict__ d, int n) {
    int idx = (blockIdx.x * 256 + threadIdx.x) * 4;
    if (idx >= n) return;
    float4 v = *reinterpret_cast<const float4*>(s + idx);
    ushort4 o;
    o.x = f2bf(v.x); o.y = f2bf(v.y); o.z = f2bf(v.z); o.w = f2bf(v.w);
    *reinterpret_cast<ushort4*>(d + idx) = o;
}

// tiled transpose-cast: dst[c][r] (bf16) = src[r][c] (fp32); batch via z
__global__ __launch_bounds__(256) void k_transp(const float* __restrict__ src,
                                                unsigned short* __restrict__ dst,
                                                int R, int Cc,
                                                long long sSrc, long long sDst) {
    src += (size_t)blockIdx.z * sSrc;
    dst += (size_t)blockIdx.z * sDst;
    __shared__ float t[32][33];
    const int tx = threadIdx.x & 31, ty = threadIdx.x >> 5;  // ty 0..7
    const int r0 = blockIdx.y * 32, c0 = blockIdx.x * 32;
#pragma unroll
    for (int r = 0; r < 4; ++r)
        t[ty + r * 8][tx] = src[(size_t)(r0 + ty + r * 8) * Cc + c0 + tx];
    __syncthreads();
#pragma unroll
    for (int r = 0; r < 4; ++r)
        dst[(size_t)(c0 + ty + r * 8) * R + r0 + tx] = f2bf(t[tx][ty + r * 8]);
}

// Pack glu_w into MFMA B-fragment layout with INTERLEAVED a/g columns:
// frag col j: j=2u -> a-col q*64+w*8+u ; j=2u+1 -> g-col 512+q*64+w*8+u.
// dst[((l*8+q)*8+w)*16+kt][lane]: pairs p -> k = 32kt+8*(lane>>4)+2p(+1).
__global__ __launch_bounds__(256) void k_pack2(const float* __restrict__ src,
                                               uint4* __restrict__ dst) {
    const int blk = blockIdx.x;            // l*64 + q*8 + w   (512 blocks)
    const int w = blk & 7, q = (blk >> 3) & 7, l = blk >> 6;
    const float* wl = src + (size_t)l * nD * 1024;
    for (int i = threadIdx.x; i < 16 * 64; i += 256) {
        const int kt = i >> 6, ln = i & 63;
        const int j = ln & 15, g = ln >> 4;
        const int u = j >> 1;
        const int col = (j & 1) ? (512 + q * 64 + w * 8 + u)
                                : (q * 64 + w * 8 + u);
        const int k0 = 32 * kt + 8 * g;
        unsigned pr[4];
#pragma unroll
        for (int p = 0; p < 4; ++p) {
            float a = wl[(size_t)(k0 + 2 * p) * 1024 + col];
            float c = wl[(size_t)(k0 + 2 * p + 1) * 1024 + col];
            pr[p] = (unsigned)f2bf(a) | ((unsigned)f2bf(c) << 16);
        }
        dst[((((size_t)l * 8 + q) * 8 + w) * 16 + kt) * 64 + ln] =
            make_uint4(pr[0], pr[1], pr[2], pr[3]);
    }
}

// ---------------------------------------------------------------------------
// bf16 MFMA GEMM: C[m,n] = act( sum_k A[m,k]*B[k,n] + bias[n] ).
// A: bf16 [M][K] row-major. Bt: bf16 [N][K] (pre-transposed). C: fp32.
// 128x128 tile, BK=32, 4 waves (2x2 of 64x64), 16x16x32 MFMA.
// Fragment layouts HW-verified by the scan kernel (R5/R8 absmax).
// ---------------------------------------------------------------------------
template<int ACT>
__global__ __launch_bounds__(256) void k_gemm_bf(
    const unsigned short* __restrict__ A, int lda, long long sA,
    const unsigned short* __restrict__ Bt, int ldb, long long sB,
    const float* __restrict__ bias, long long sBias,
    float* __restrict__ C, int ldc, long long sC,
    int M, int N, int K)
{
    A  += (size_t)blockIdx.z * sA;
    Bt += (size_t)blockIdx.z * sB;
    C  += (size_t)blockIdx.z * sC;
    const float* biasp = bias ? bias + (size_t)blockIdx.z * sBias : nullptr;

    __shared__ __align__(16) unsigned short A_s[128][40];  // +8 pad: 2-way only
    __shared__ __align__(16) unsigned short B_s[128][40];
    const int tid = threadIdx.x, lane = tid & 63;
    const int wv = tid >> 6;
    const int wm = (wv >> 1) * 64, wn = (wv & 1) * 64;
    const int bm = blockIdx.y * 128, bn = blockIdx.x * 128;
    const int srow = tid >> 2, sc8 = (tid & 3) * 8;

    f32x4 acc[4][4];
#pragma unroll
    for (int i = 0; i < 4; ++i)
#pragma unroll
        for (int j = 0; j < 4; ++j) acc[i][j] = f32x4{0.f, 0.f, 0.f, 0.f};

    const int fr = lane & 15, fg = (lane >> 4) * 8;

    for (int kt = 0; kt < K; kt += 32) {
        uint4 a0 = *reinterpret_cast<const uint4*>(A + (size_t)(bm + srow) * lda + kt + sc8);
        uint4 a1 = *reinterpret_cast<const uint4*>(A + (size_t)(bm + srow + 64) * lda + kt + sc8);
        uint4 b0 = *reinterpret_cast<const uint4*>(Bt + (size_t)(bn + srow) * ldb + kt + sc8);
        uint4 b1 = *reinterpret_cast<const uint4*>(Bt + (size_t)(bn + srow + 64) * ldb + kt + sc8);
        __syncthreads();
        *reinterpret_cast<uint4*>(&A_s[srow][sc8]) = a0;
        *reinterpret_cast<uint4*>(&A_s[srow + 64][sc8]) = a1;
        *reinterpret_cast<uint4*>(&B_s[srow][sc8]) = b0;
        *reinterpret_cast<uint4*>(&B_s[srow + 64][sc8]) = b1;
        __syncthreads();
        short8v af[4], bf[4];
#pragma unroll
        for (int mi = 0; mi < 4; ++mi)
            af[mi] = *reinterpret_cast<const short8v*>(&A_s[wm + mi * 16 + fr][fg]);
#pragma unroll
        for (int ni = 0; ni < 4; ++ni)
            bf[ni] = *reinterpret_cast<const short8v*>(&B_s[wn + ni * 16 + fr][fg]);
#pragma unroll
        for (int mi = 0; mi < 4; ++mi)
#pragma unroll
            for (int ni = 0; ni < 4; ++ni)
                acc[mi][ni] = __builtin_amdgcn_mfma_f32_16x16x32_bf16(
                    af[mi], bf[ni], acc[mi][ni], 0, 0, 0);
    }

#pragma unroll
    for (int mi = 0; mi < 4; ++mi)
#pragma unroll
        for (int ni = 0; ni < 4; ++ni) {
            const int col = bn + wn + ni * 16 + (lane & 15);
            const float bv = biasp ? biasp[col] : 0.f;
#pragma unroll
            for (int p = 0; p < 4; ++p) {
                const int row = bm + wm + mi * 16 + (lane >> 4) * 4 + p;
                float v = acc[mi][ni][p] + bv;
                if (ACT == 1) v = gelu_f(v);
                C[(size_t)row * ldc + col] = v;
            }
        }
}

// ---------------------------------------------------------------------------
// Scan (unchanged from R8): tag-in-data exchange, register-resident weights.
// ---------------------------------------------------------------------------
__global__ __launch_bounds__(512, 1) void k_scan7(
    const float* __restrict__ tokens,      // [B,T,L,D]
    const uint4* __restrict__ wswz,        // packed B-fragments (interleaved)
    const float* __restrict__ glu_b,       // [L,2D]
    const float* __restrict__ sc_sum, const float* __restrict__ ii_sum,
    const float* __restrict__ ln_glu_g, const float* __restrict__ ln_glu_b,
    const float* __restrict__ ln_state_g, const float* __restrict__ ln_state_b,
    float* __restrict__ vout,              // [B,T,L,D] raw v (fp32, plain)
    unsigned int* __restrict__ recs)
{
    const int l = blockIdx.x & 7, q = blockIdx.x >> 3;
    const int tid = threadIdx.x, w = tid >> 6, lane = tid & 63;
    const int b = w;  // wave = batch

    __shared__ __align__(16) unsigned hn_pk[8][260];       // bf16 pairs, padded
    __shared__ __align__(16) unsigned zbuf[4];
    __shared__ __align__(16) unsigned short vrow[8][512];  // consumer v (bf16)
    __shared__ __align__(16) unsigned short vstage[8][64]; // producer stage
    __shared__ __align__(16) float vsq[8][8][2];           // [b][w]{S,Q}

    uint4 wr[16];
    {
        const uint4* wp = wswz + ((((size_t)l * 8 + q) * 8 + w) * 16) * 64 + lane;
#pragma unroll
        for (int kt = 0; kt < 16; ++kt) wr[kt] = wp[kt * 64];
    }
    const int d0 = lane * 8;
    float P_sc[8], P_ii[8], P_gg[8], P_gb[8], P_sg[8], P_sb[8];
#pragma unroll
    for (int j = 0; j < 8; j += 4) {
        *reinterpret_cast<float4*>(&P_sc[j]) = *reinterpret_cast<const float4*>(sc_sum + l * nD + d0 + j);
        *reinterpret_cast<float4*>(&P_ii[j]) = *reinterpret_cast<const float4*>(ii_sum + l * nD + d0 + j);
        *reinterpret_cast<float4*>(&P_gg[j]) = *reinterpret_cast<const float4*>(ln_glu_g + d0 + j);
        *reinterpret_cast<float4*>(&P_gb[j]) = *reinterpret_cast<const float4*>(ln_glu_b + d0 + j);
        *reinterpret_cast<float4*>(&P_sg[j]) = *reinterpret_cast<const float4*>(ln_state_g + d0 + j);
        *reinterpret_cast<float4*>(&P_sb[j]) = *reinterpret_cast<const float4*>(ln_state_b + d0 + j);
    }
    const int cu = (lane & 15) >> 1;
    const int mycol = (lane & 1) ? (512 + q * 64 + w * 8 + cu)
                                 : (q * 64 + w * 8 + cu);
    const float bias_c = glu_b[l * 1024 + mycol];
    const int vcol = q * 64 + w * 8 + cu;

    if (tid < 4) zbuf[tid] = 0u;

    const float* tokp = tokens + ((size_t)b * nT * nL + l) * nD + d0;

    const unsigned* afp; int astep;
    {
        int bb = lane & 15, g = lane >> 4;
        if (bb < 8) { afp = &hn_pk[bb][g * 4]; astep = 16; }
        else        { afp = &zbuf[0];          astep = 0;  }
    }
    __syncthreads();

    float4 tk0 = *reinterpret_cast<const float4*>(tokp);
    float4 tk1 = *reinterpret_cast<const float4*>(tokp + 4);

    for (int t = 0; t < nT; ++t) {
        float tk[8] = {tk0.x, tk0.y, tk0.z, tk0.w, tk1.x, tk1.y, tk1.z, tk1.w};
        float h[8];
        if (t > 0) {
            const unsigned* rp = recs + ((((size_t)((t - 1) & 1) * nL + l) * nB + b) * 128) * 4;
            const unsigned* pa = rp + lane * 4;
            const unsigned* pb = rp + (lane + 64) * 4;
            u32x4 ra, rb;
            int ok;
            do {
                asm volatile(
                    "global_load_dwordx4 %0, %2, off sc0 sc1\n\t"
                    "global_load_dwordx4 %1, %3, off sc0 sc1\n\t"
                    "s_waitcnt vmcnt(0)"
                    : "=&v"(ra), "=&v"(rb)
                    : "v"(pa), "v"(pb)
                    : "memory");
                ok = (ra[3] == (unsigned)t) && (rb[3] == (unsigned)t);
            } while (!__all(ok));

            float S = 0.f, Q = 0.f;
            if (lane & 1) {
                S = __uint_as_float(ra[1]) + __uint_as_float(rb[1]);
                Q = __uint_as_float(ra[2]) + __uint_as_float(rb[2]);
            }
#pragma unroll
            for (int o = 32; o > 0; o >>= 1) { S += __shfl_xor(S, o, 64); Q += __shfl_xor(Q, o, 64); }
            const float mv = S * (1.f / nD);
            const float iv = rsqrtf(Q * (1.f / nD) - mv * mv + 1e-5f);

            {
                const int ia = lane, ib2 = lane + 64;
                const int qa = ia >> 4, wa = (ia >> 1) & 7, ja = ia & 1;
                const int qb2 = ib2 >> 4, wb2 = (ib2 >> 1) & 7;
                unsigned* da = reinterpret_cast<unsigned*>(&vrow[b][qa * 64 + wa * 8 + ja * 6]);
                unsigned* db = reinterpret_cast<unsigned*>(&vrow[b][qb2 * 64 + wb2 * 8 + ja * 6]);
                if (!ja) {
                    da[0] = ra[0]; da[1] = ra[1]; da[2] = ra[2];
                    db[0] = rb[0]; db[1] = rb[1]; db[2] = rb[2];
                } else {
                    da[0] = ra[0];
                    db[0] = rb[0];
                }
            }
            asm volatile("s_waitcnt lgkmcnt(0)" ::: "memory");
            __builtin_amdgcn_sched_barrier(0);
            uint4 pv = *reinterpret_cast<const uint4*>(&vrow[b][lane * 8]);
            float vv[8];
            vv[0] = bfu2f((unsigned short)(pv.x & 0xffffu));
            vv[1] = bfu2f((unsigned short)(pv.x >> 16));
            vv[2] = bfu2f((unsigned short)(pv.y & 0xffffu));
            vv[3] = bfu2f((unsigned short)(pv.y >> 16));
            vv[4] = bfu2f((unsigned short)(pv.z & 0xffffu));
            vv[5] = bfu2f((unsigned short)(pv.z >> 16));
            vv[6] = bfu2f((unsigned short)(pv.w & 0xffffu));
            vv[7] = bfu2f((unsigned short)(pv.w >> 16));
#pragma unroll
            for (int j = 0; j < 8; ++j) {
                float st = (vv[j] - mv) * iv * P_sg[j] + P_sb[j];
                h[j] = st * P_sc[j] + tk[j] * P_ii[j];
            }
        } else {
#pragma unroll
            for (int j = 0; j < 8; ++j) h[j] = tk[j] * P_ii[j];
        }

        if (t + 1 < nT) {
            tk0 = *reinterpret_cast<const float4*>(tokp + (size_t)(t + 1) * nLD);
            tk1 = *reinterpret_cast<const float4*>(tokp + (size_t)(t + 1) * nLD + 4);
        }

        float S = 0.f, Q = 0.f;
#pragma unroll
        for (int j = 0; j < 8; ++j) { S += h[j]; Q += h[j] * h[j]; }
#pragma unroll
        for (int o = 32; o > 0; o >>= 1) { S += __shfl_xor(S, o, 64); Q += __shfl_xor(Q, o, 64); }
        const float mh = S * (1.f / nD);
        const float ih = rsqrtf(Q * (1.f / nD) - mh * mh + 1e-5f);
        unsigned pr[4];
#pragma unroll
        for (int p = 0; p < 4; ++p) {
            float a0 = (h[2 * p]     - mh) * ih * P_gg[2 * p]     + P_gb[2 * p];
            float a1 = (h[2 * p + 1] - mh) * ih * P_gg[2 * p + 1] + P_gb[2 * p + 1];
            pr[p] = (unsigned)f2bf(a0) | ((unsigned)f2bf(a1) << 16);
        }
        *reinterpret_cast<uint4*>(&hn_pk[b][lane * 4]) = make_uint4(pr[0], pr[1], pr[2], pr[3]);

        asm volatile("s_waitcnt lgkmcnt(0)" ::: "memory");
        __builtin_amdgcn_s_barrier();
        __builtin_amdgcn_sched_barrier(0);

        f32x4 acc0 = {0.f, 0.f, 0.f, 0.f}, acc1 = {0.f, 0.f, 0.f, 0.f};
#pragma unroll
        for (int kt = 0; kt < 8; ++kt) {
            short8v a0 = *reinterpret_cast<const short8v*>(afp + (2 * kt) * astep);
            short8v a1 = *reinterpret_cast<const short8v*>(afp + (2 * kt + 1) * astep);
            acc0 = __builtin_amdgcn_mfma_f32_16x16x32_bf16(
                a0, __builtin_bit_cast(short8v, wr[2 * kt]), acc0, 0, 0, 0);
            acc1 = __builtin_amdgcn_mfma_f32_16x16x32_bf16(
                a1, __builtin_bit_cast(short8v, wr[2 * kt + 1]), acc1, 0, 0, 0);
        }

        float x[4], y[4];
#pragma unroll
        for (int i = 0; i < 4; ++i) x[i] = acc0[i] + acc1[i] + bias_c;
#pragma unroll
        for (int i = 0; i < 4; ++i) y[i] = __shfl_xor(x[i], 1, 64);
        float sv[4], sq[4];
        const int r0 = (lane >> 4) * 4;
        const bool prod = (lane < 32) && !(lane & 1);
#pragma unroll
        for (int i = 0; i < 4; ++i) {
            float v = x[i] / (1.f + __expf(-y[i]));
            sv[i] = prod ? v : 0.f;
            sq[i] = prod ? v * v : 0.f;
            if (prod) {
                vout[(((size_t)(r0 + i) * nT + t) * nL + l) * nD + vcol] = v;
                vstage[r0 + i][w * 8 + cu] = f2bf(v);
            }
        }
#pragma unroll
        for (int i = 0; i < 4; ++i) {
            sv[i] += __shfl_xor(sv[i], 2, 64); sq[i] += __shfl_xor(sq[i], 2, 64);
            sv[i] += __shfl_xor(sv[i], 4, 64); sq[i] += __shfl_xor(sq[i], 4, 64);
            sv[i] += __shfl_xor(sv[i], 8, 64); sq[i] += __shfl_xor(sq[i], 8, 64);
        }
        if (lane == 0 || lane == 16) {
#pragma unroll
            for (int i = 0; i < 4; ++i) {
                vsq[r0 + i][w][0] = sv[i];
                vsq[r0 + i][w][1] = sq[i];
            }
        }

        asm volatile("s_waitcnt lgkmcnt(0)" ::: "memory");
        __builtin_amdgcn_s_barrier();
        __builtin_amdgcn_sched_barrier(0);

        if (tid < 128) {
            const int bb = tid >> 4, wb = (tid >> 1) & 7, jb = tid & 1;
            const unsigned* vp = reinterpret_cast<const unsigned*>(&vstage[bb][wb * 8]);
            u32x4 rec;
            if (!jb) { rec[0] = vp[0]; rec[1] = vp[1]; rec[2] = vp[2]; }
            else {
                rec[0] = vp[3];
                rec[1] = __float_as_uint(vsq[bb][wb][0]);
                rec[2] = __float_as_uint(vsq[bb][wb][1]);
            }
            rec[3] = (unsigned)(t + 1);
            unsigned* dst = recs + (((((size_t)(t & 1) * nL + l) * nB + bb) * 128)
                                    + q * 16 + wb * 2 + jb) * 4;
            asm volatile("global_store_dwordx4 %0, %1, off sc0 sc1"
                         :: "v"(dst), "v"(rec) : "memory");
        }
    }
}

// y = LN_ff( LN_state(raw v) * os_sum[l] ); OUTPUT bf16 (feeds MFMA ff1 GEMM)
__global__ __launch_bounds__(256) void k_y2(
    const float* __restrict__ vout, const float* __restrict__ os_sum,
    const float* __restrict__ lsg, const float* __restrict__ lsb,
    const float* __restrict__ fg, const float* __restrict__ fb,
    unsigned short* __restrict__ y)
{
    const int row = blockIdx.x * 4 + (threadIdx.x >> 6);   // over B*T*L
    const int lane = threadIdx.x & 63;
    const int l = row & 7;

    const float* vp = vout + (size_t)row * nD;
    const int base = lane * 8;
    float vv[8];
    *reinterpret_cast<float4*>(&vv[0]) = *reinterpret_cast<const float4*>(vp + base);
    *reinterpret_cast<float4*>(&vv[4]) = *reinterpret_cast<const float4*>(vp + base + 4);
    float S = 0.f, Q = 0.f;
#pragma unroll
    for (int j = 0; j < 8; ++j) { S += vv[j]; Q += vv[j] * vv[j]; }
#pragma unroll
    for (int o = 32; o > 0; o >>= 1) { S += __shfl_xor(S, o, 64); Q += __shfl_xor(Q, o, 64); }
    const float mv = S * (1.f / nD);
    const float iv = rsqrtf(Q * (1.f / nD) - mv * mv + 1e-5f);

    const float* op = os_sum + l * nD;
    float val[8];
    float s2 = 0.f, q2 = 0.f;
#pragma unroll
    for (int j = 0; j < 8; j += 4) {
        float4 o4 = *reinterpret_cast<const float4*>(op + base + j);
        float4 g4 = *reinterpret_cast<const float4*>(lsg + base + j);
        float4 b4 = *reinterpret_cast<const float4*>(lsb + base + j);
        val[j]     = ((vv[j]     - mv) * iv * g4.x + b4.x) * o4.x;
        val[j + 1] = ((vv[j + 1] - mv) * iv * g4.y + b4.y) * o4.y;
        val[j + 2] = ((vv[j + 2] - mv) * iv * g4.z + b4.z) * o4.z;
        val[j + 3] = ((vv[j + 3] - mv) * iv * g4.w + b4.w) * o4.w;
    }
#pragma unroll
    for (int j = 0; j < 8; ++j) { s2 += val[j]; q2 += val[j] * val[j]; }
#pragma unroll
    for (int o = 32; o > 0; o >>= 1) { s2 += __shfl_xor(s2, o, 64); q2 += __shfl_xor(q2, o, 64); }
    const float m2 = s2 * (1.f / nD);
    const float i2 = rsqrtf(q2 * (1.f / nD) - m2 * m2 + 1e-5f);
    const float* gp = fg + l * nD;
    const float* bp = fb + l * nD;
    unsigned short* yp = y + (size_t)row * nD;
    unsigned pk[4];
#pragma unroll
    for (int j = 0; j < 8; j += 4) {
        float4 g4 = *reinterpret_cast<const float4*>(gp + base + j);
        float4 b4 = *reinterpret_cast<const float4*>(bp + base + j);
        float o0 = (val[j]     - m2) * i2 * g4.x + b4.x;
        float o1 = (val[j + 1] - m2) * i2 * g4.y + b4.y;
        float o2 = (val[j + 2] - m2) * i2 * g4.z + b4.z;
        float o3 = (val[j + 3] - m2) * i2 * g4.w + b4.w;
        pk[j / 4 * 2]     = (unsigned)f2bf(o0) | ((unsigned)f2bf(o1) << 16);
        pk[j / 4 * 2 + 1] = (unsigned)f2bf(o2) | ((unsigned)f2bf(o3) << 16);
    }
    *reinterpret_cast<uint4*>(yp + base) = make_uint4(pk[0], pk[1], pk[2], pk[3]);
}

// scores from h via w2a; softmax over L; write scaled h as bf16; store probs
__global__ __launch_bounds__(256) void k_scores(
    const float* __restrict__ h, const float* __restrict__ w2a,
    const float* __restrict__ c2, const float* __restrict__ attn_b,
    unsigned short* __restrict__ hbf, float* __restrict__ scores)
{
    const int bt = blockIdx.x;
    const int tid = threadIdx.x, wid = tid >> 6, lane = tid & 63;
    __shared__ float slog[nL];
    const float* hrow = h + (size_t)bt * nLD;
    for (int l = wid; l < nL; l += 4) {
        const float* hp = hrow + l * nD;
        const float* wp = w2a + l * nD;
        float s = 0.f;
        for (int i = lane; i < nD; i += 64) s += hp[i] * wp[i];
#pragma unroll
        for (int off = 32; off > 0; off >>= 1) s += __shfl_down(s, off, 64);
        if (lane == 0) slog[l] = s + c2[l] + attn_b[0];
    }
    __syncthreads();
    float mx = -1e30f;
#pragma unroll
    for (int l = 0; l < nL; ++l) mx = fmaxf(mx, slog[l]);
    float den = 0.f;
#pragma unroll
    for (int l = 0; l < nL; ++l) den += __expf(slog[l] - mx);
    float rden = 1.f / den;
    unsigned short* obase = hbf + (size_t)bt * nLD;
#pragma unroll
    for (int it = 0; it < 4; ++it) {
        int idx = tid * 4 + it * 1024;
        int l = idx >> 9;
        float s = __expf(slog[l] - mx) * rden;
        float4 v = *reinterpret_cast<const float4*>(hrow + idx);
        unsigned p0 = (unsigned)f2bf(v.x * s) | ((unsigned)f2bf(v.y * s) << 16);
        unsigned p1 = (unsigned)f2bf(v.z * s) | ((unsigned)f2bf(v.w * s) << 16);
        *reinterpret_cast<uint2*>(obase + idx) = make_uint2(p0, p1);
    }
    if (tid < nL) scores[bt * nL + tid] = __expf(slog[tid] - mx) * rden;
}

// out = LN( wbuf + sum_l s_l * ff_b2[l] ) with ln_emb params
__global__ __launch_bounds__(256) void k_final(
    const float* __restrict__ wbuf, const float* __restrict__ scores,
    const float* __restrict__ ff_b2, const float* __restrict__ g,
    const float* __restrict__ bvec, float* __restrict__ out)
{
    const int bt = blockIdx.x;
    const int tid = threadIdx.x;
    __shared__ float ssc[nL];
    __shared__ float red[8];
    if (tid < nL) ssc[tid] = scores[bt * nL + tid];
    __syncthreads();
    const int e0 = tid * 4;
    float4 w = *reinterpret_cast<const float4*>(wbuf + (size_t)bt * nE + e0);
#pragma unroll
    for (int l = 0; l < nL; ++l) {
        float s = ssc[l];
        float4 b2 = *reinterpret_cast<const float4*>(ff_b2 + l * nE + e0);
        w.x += s * b2.x; w.y += s * b2.y; w.z += s * b2.z; w.w += s * b2.w;
    }
    float sum = w.x + w.y + w.z + w.w;
    float sq = w.x * w.x + w.y * w.y + w.z * w.z + w.w * w.w;
    int wid = tid >> 6, lane = tid & 63;
#pragma unroll
    for (int off = 32; off > 0; off >>= 1) {
        sum += __shfl_down(sum, off, 64); sq += __shfl_down(sq, off, 64);
    }
    if (lane == 0) { red[wid] = sum; red[4 + wid] = sq; }
    __syncthreads();
    sum = red[0] + red[1] + red[2] + red[3];
    sq  = red[4] + red[5] + red[6] + red[7];
    float mean = sum * (1.f / nE);
    float inv = rsqrtf(sq * (1.f / nE) - mean * mean + 1e-5f);
    float4 g4 = *reinterpret_cast<const float4*>(g + e0);
    float4 b4 = *reinterpret_cast<const float4*>(bvec + e0);
    float4 o;
    o.x = (w.x - mean) * inv * g4.x + b4.x;
    o.y = (w.y - mean) * inv * g4.y + b4.y;
    o.z = (w.z - mean) * inv * g4.z + b4.z;
    o.w = (w.w - mean) * inv * g4.w + b4.w;
    *reinterpret_cast<float4*>(out + (size_t)bt * nE + e0) = o;
}

extern "C" void kernel_launch(void* const* d_in, const int* in_sizes, int n_in,
                              void* d_out, int out_size, void* d_ws, size_t ws_size,
                              hipStream_t stream) {
    (void)in_sizes; (void)n_in; (void)out_size; (void)ws_size;
    const float* emb            = (const float*)d_in[0];
    const float* state_control  = (const float*)d_in[1];
    const float* input_influence= (const float*)d_in[2];
    const float* output_shaper  = (const float*)d_in[3];
    const float* glu_w          = (const float*)d_in[4];
    const float* glu_b          = (const float*)d_in[5];
    const float* e2s_w          = (const float*)d_in[6];
    const float* e2s_b          = (const float*)d_in[7];
    const float* ln_glu_g       = (const float*)d_in[8];
    const float* ln_glu_b       = (const float*)d_in[9];
    const float* ln_state_g     = (const float*)d_in[10];
    const float* ln_state_b     = (const float*)d_in[11];
    const float* ln_emb_g       = (const float*)d_in[12];
    const float* ln_emb_b       = (const float*)d_in[13];
    const float* ff_ln_g        = (const float*)d_in[14];
    const float* ff_ln_b        = (const float*)d_in[15];
    const float* ff_w1          = (const float*)d_in[16];
    const float* ff_b1          = (const float*)d_in[17];
    const float* ff_w2          = (const float*)d_in[18];
    const float* ff_b2          = (const float*)d_in[19];
    const float* attn_w         = (const float*)d_in[20];
    const float* attn_b         = (const float*)d_in[21];

    // workspace layout (~160 MB)
    char* ws = (char*)d_ws;
    float* tokens = (float*)ws;  ws += (size_t)nBT * nLD * 4;             // 67 MB
    float* vbuf   = (float*)ws;  ws += (size_t)nBT * nLD * 4;             // 67 MB
    uint4* wswz   = (uint4*)ws;  ws += (size_t)nL * 8 * 8 * 16 * 64 * 16; // 8 MB
    unsigned int* recs = (unsigned int*)ws; ws += (size_t)2 * nL * nB * 128 * 16;  // 256 KB
    unsigned short* w1T = (unsigned short*)ws; ws += (size_t)nL * nD * nD * 2;     // 4 MB
    unsigned short* w2T = (unsigned short*)ws; ws += (size_t)nE * nLD * 2;         // 8 MB
    float* sc_sum = (float*)ws;  ws += nLD * 4;
    float* ii_sum = (float*)ws;  ws += nLD * 4;
    float* os_sum = (float*)ws;  ws += nLD * 4;
    float* w2a    = (float*)ws;  ws += nLD * 4;
    float* c2     = (float*)ws;  ws += 256;
    float* scores = (float*)ws;  ws += (size_t)nBT * nL * 4;
    // aliases:
    unsigned short* emb_bf = (unsigned short*)vbuf;                    // dead before scan writes v
    unsigned short* e2sT   = (unsigned short*)vbuf + (size_t)nBT * nE; // ditto (8 MB further)
    unsigned short* ybf    = (unsigned short*)tokens;                  // tokens dead after scan
    unsigned short* hbf    = (unsigned short*)tokens + (size_t)nBT * nLD;  // upper half
    float* wbuf = tokens;  // ybf dead after ff1 GEMM; disjoint from hbf

    // precompute
    k_init2<<<64, 256, 0, stream>>>(recs);
    k_pack2<<<nL * 64, 256, 0, stream>>>(glu_w, wswz);
    k_wdot<<<1024, 256, 0, stream>>>(state_control, nullptr, sc_sum, nLD, nD);
    k_wdot<<<1024, 256, 0, stream>>>(input_influence, nullptr, ii_sum, nLD, nD);
    k_wdot<<<1024, 256, 0, stream>>>(output_shaper, nullptr, os_sum, nLD, nD);
    k_wdot<<<1024, 256, 0, stream>>>(ff_w2, attn_w, w2a, nLD, nE);
    k_wdot<<<2, 256, 0, stream>>>(ff_b2, attn_w, c2, nL, nE);
    k_cast<<<nBT * nE / 1024, 256, 0, stream>>>(emb, emb_bf, nBT * nE);
    k_transp<<<dim3(nLD / 32, nE / 32, 1), 256, 0, stream>>>(e2s_w, e2sT, nE, nLD, 0, 0);
    k_transp<<<dim3(nD / 32, nD / 32, nL), 256, 0, stream>>>(ff_w1, w1T, nD, nD,
                                                             (long long)nD * nD, (long long)nD * nD);
    k_transp<<<dim3(nE / 32, nLD / 32, 1), 256, 0, stream>>>(ff_w2, w2T, nLD, nE, 0, 0);

    // tokens = emb @ e2s_w + e2s_b   [4096 x 4096], K=1024  (bf16 MFMA)
    k_gemm_bf<0><<<dim3(32, 32, 1), 256, 0, stream>>>(
        emb_bf, nE, 0, e2sT, nE, 0, e2s_b, 0, tokens, nLD, 0, nBT, nLD, nE);

    // distributed recurrent scan -> raw v
    k_scan7<<<64, 512, 0, stream>>>(tokens, wswz, glu_b, sc_sum, ii_sum,
                                    ln_glu_g, ln_glu_b, ln_state_g, ln_state_b,
                                    vbuf, recs);

    // y = LN_ff(LN_state(v) * os_sum) -> bf16 ybf
    k_y2<<<nBT * nL / 4, 256, 0, stream>>>(vbuf, os_sum,
                                           ln_state_g, ln_state_b,
                                           ff_ln_g, ff_ln_b, ybf);

    // h = GELU(y @ ff_w1 + ff_b1), per-layer batched (bf16 MFMA) -> vbuf fp32
    k_gemm_bf<1><<<dim3(4, 32, 8), 256, 0, stream>>>(
        ybf, nLD, nD, w1T, nD, (long long)nD * nD, ff_b1, nD,
        vbuf, nLD, nD, nBT, nD, nD);

    // scores; scaled h -> bf16 hbf
    k_scores<<<nBT, 256, 0, stream>>>(vbuf, w2a, c2, attn_b, hbf, scores);

    // weighted = (s*h) @ W2cat   [4096 x 1024], K=4096 (bf16 MFMA) -> wbuf
    k_gemm_bf<0><<<dim3(8, 32, 1), 256, 0, stream>>>(
        hbf, nLD, 0, w2T, nLD, 0, nullptr, 0, wbuf, nE, 0, nBT, nE, nLD);

    // out = LN(weighted + sum_l s_l*ff_b2[l])
    k_final<<<nBT, 256, 0, stream>>>(wbuf, scores, ff_b2, ln_emb_g, ln_emb_b, (float*)d_out);
}